// Round 2
// baseline (1058.734 us; speedup 1.0000x reference)
//
#include <hip/hip_runtime.h>

#define N_NODES 100000
#define NEDGE   3200000
#define F_IN    512
#define HID     16
#define NCLS    40

/* ---- dst-bucket partition geometry ---- */
#define BSHIFT  8
#define BNODES  256                                  /* nodes per bucket */
#define NBUCK   ((N_NODES + BNODES - 1) / BNODES)    /* 391 */
#define BCAP    8832    /* mean 8192, sd ~90 -> +7 sigma; keeps ws under proven 27.2 MB */
#define EPB     5120    /* edges per partition block: 256 thr x 4 x 5 */
#define NPART   (NEDGE / EPB)                        /* 625, exact */

typedef __bf16 bf16x8 __attribute__((ext_vector_type(8)));
typedef float floatx4 __attribute__((ext_vector_type(4)));

/* ---------------- edge partition by dst bucket ----------------
 * Per block: LDS histogram over 391 buckets, ONE global atomic per
 * (block,bucket) to reserve a run, then append-scatter packed entries
 * (ldst<<17 | src, 25 bits) into the bucket region. Replaces
 * deg/scan/fill/col: 1x edge read (was 9x), no per-edge device atomics,
 * append-ordered writes instead of random 4B scatter. */
__global__ __launch_bounds__(256) void k_part(const int* __restrict__ src,
                                              const int* __restrict__ dst,
                                              int* __restrict__ gcnt,
                                              int* __restrict__ ebuf) {
    __shared__ int hist[NBUCK];
    int t = threadIdx.x;
    for (int i = t; i < NBUCK; i += 256) hist[i] = 0;
    __syncthreads();

    int base = blockIdx.x * EPB + t * 4;
    int4 dr[5];
    #pragma unroll
    for (int s = 0; s < 5; s++) {
        dr[s] = *(const int4*)(dst + base + s * 1024);
        atomicAdd(&hist[dr[s].x >> BSHIFT], 1);
        atomicAdd(&hist[dr[s].y >> BSHIFT], 1);
        atomicAdd(&hist[dr[s].z >> BSHIFT], 1);
        atomicAdd(&hist[dr[s].w >> BSHIFT], 1);
    }
    __syncthreads();

    /* reserve runs; hist[i] becomes this block's absolute cursor in bucket i */
    for (int i = t; i < NBUCK; i += 256) {
        int h = hist[i];
        hist[i] = h ? atomicAdd(&gcnt[i], h) : 0;
    }
    __syncthreads();

    #pragma unroll
    for (int s = 0; s < 5; s++) {
        int4 s4 = *(const int4*)(src + base + s * 1024);
        int dd[4] = {dr[s].x, dr[s].y, dr[s].z, dr[s].w};
        int ss[4] = {s4.x, s4.y, s4.z, s4.w};
        #pragma unroll
        for (int j = 0; j < 4; j++) {
            int d = dd[j];
            int b = d >> BSHIFT;
            int p = atomicAdd(&hist[b], 1);
            ebuf[b * BCAP + p] = ((d & (BNODES - 1)) << 17) | ss[j];
        }
    }
}

/* ---------------- per-bucket degree -> dinv (LDS-local atomics) ---------------- */
__global__ __launch_bounds__(256) void k_bdeg(const int* __restrict__ gcnt,
                                              const int* __restrict__ ebuf,
                                              float* __restrict__ dinv) {
    __shared__ int cnt[BNODES];
    int b = blockIdx.x, t = threadIdx.x;
    cnt[t] = 0;
    __syncthreads();
    int ne = gcnt[b];
    const int* e = ebuf + b * BCAP;
    for (int i = t; i < ne; i += 256) atomicAdd(&cnt[e[i] >> 17], 1);
    __syncthreads();
    int v = b * BNODES + t;
    if (v < N_NODES) dinv[v] = rsqrtf((float)(cnt[t] + 1));   /* +1 self loop */
}

/* ---------------- GEMM1: h1s = dinv * (x @ W1), bf16 MFMA hi/lo split ---------------- */
__global__ __launch_bounds__(256) void k_gemm1(const float* __restrict__ x,
                                               const float* __restrict__ W1,
                                               const float* __restrict__ dinv,
                                               float* __restrict__ h1s) {
    __shared__ __bf16 wh[16 * 64 * 8];
    __shared__ __bf16 wl[16 * 64 * 8];
    int t = threadIdx.x;
    for (int e = t; e < 8192; e += 256) {
        int c = e >> 9, l = (e >> 3) & 63, j = e & 7;
        int k = c * 32 + ((l >> 4) << 3) + j;
        int n = l & 15;
        float wv = W1[k * HID + n];
        __bf16 h = (__bf16)wv;
        wh[e] = h;
        wl[e] = (__bf16)(wv - (float)h);
    }
    __syncthreads();

    int wave = t >> 6, lane = t & 63;
    int q = lane >> 4, m = lane & 15;
    int row0 = blockIdx.x * 64 + wave * 16;
    int rowa = row0 + m;
    if (rowa >= N_NODES) rowa = N_NODES - 1;
    const float* xr = x + (size_t)rowa * F_IN + q * 8;

    floatx4 acc = {0.f, 0.f, 0.f, 0.f};
    #pragma unroll 4
    for (int c = 0; c < 16; c++) {
        float4 a0 = *(const float4*)(xr + c * 32);
        float4 a1 = *(const float4*)(xr + c * 32 + 4);
        float xv[8] = {a0.x, a0.y, a0.z, a0.w, a1.x, a1.y, a1.z, a1.w};
        bf16x8 ah, al;
        #pragma unroll
        for (int j = 0; j < 8; j++) {
            __bf16 h = (__bf16)xv[j];
            ah[j] = h;
            al[j] = (__bf16)(xv[j] - (float)h);
        }
        bf16x8 bh = *(const bf16x8*)&wh[(c * 64 + lane) * 8];
        bf16x8 bl = *(const bf16x8*)&wl[(c * 64 + lane) * 8];
        acc = __builtin_amdgcn_mfma_f32_16x16x32_bf16(ah, bh, acc, 0, 0, 0);
        acc = __builtin_amdgcn_mfma_f32_16x16x32_bf16(ah, bl, acc, 0, 0, 0);
        acc = __builtin_amdgcn_mfma_f32_16x16x32_bf16(al, bh, acc, 0, 0, 0);
    }
    #pragma unroll
    for (int r = 0; r < 4; r++) {
        int grow = row0 + q * 4 + r;
        if (grow < N_NODES) h1s[grow * HID + (lane & 15)] = dinv[grow] * acc[r];
    }
}

/* ---------------- layer-1 aggregate: one WG per bucket, LDS accumulator ----------------
 * acc stride 17 breaks the (node*16+k)%32 bank aliasing of stride 16.
 * Edge-parallel, 512 threads for MLP: each thread owns whole edges ->
 * 4x dwordx4 gather + 16 ds_add_f32. Epilogue: bias+relu, pre-scale by dinv. */
__global__ __launch_bounds__(512) void k_agg1b(const float* __restrict__ h1s,
        const int* __restrict__ gcnt, const int* __restrict__ ebuf,
        const float* __restrict__ dinv, const float* __restrict__ b1,
        float* __restrict__ ys) {
    __shared__ float acc[BNODES * 17];
    __shared__ float b1s[HID];
    int t = threadIdx.x;
    for (int i = t; i < BNODES * 17; i += 512) acc[i] = 0.f;
    if (t < HID) b1s[t] = b1[t];
    __syncthreads();

    int b = blockIdx.x;
    int ne = gcnt[b];
    const int* eb = ebuf + b * BCAP;
    int i = t;
    for (; i + 512 < ne; i += 1024) {
        int e0 = eb[i], e1 = eb[i + 512];
        const float4* g0 = (const float4*)(h1s + (size_t)(e0 & 0x1FFFF) * HID);
        const float4* g1 = (const float4*)(h1s + (size_t)(e1 & 0x1FFFF) * HID);
        float v0[16], v1[16];
        *(float4*)(v0 +  0) = g0[0]; *(float4*)(v0 +  4) = g0[1];
        *(float4*)(v0 +  8) = g0[2]; *(float4*)(v0 + 12) = g0[3];
        *(float4*)(v1 +  0) = g1[0]; *(float4*)(v1 +  4) = g1[1];
        *(float4*)(v1 +  8) = g1[2]; *(float4*)(v1 + 12) = g1[3];
        float* p0 = acc + (e0 >> 17) * 17;
        float* p1 = acc + (e1 >> 17) * 17;
        #pragma unroll
        for (int k = 0; k < 16; k++) atomicAdd(p0 + k, v0[k]);
        #pragma unroll
        for (int k = 0; k < 16; k++) atomicAdd(p1 + k, v1[k]);
    }
    if (i < ne) {
        int e0 = eb[i];
        const float4* g0 = (const float4*)(h1s + (size_t)(e0 & 0x1FFFF) * HID);
        float v0[16];
        *(float4*)(v0 +  0) = g0[0]; *(float4*)(v0 +  4) = g0[1];
        *(float4*)(v0 +  8) = g0[2]; *(float4*)(v0 + 12) = g0[3];
        float* p0 = acc + (e0 >> 17) * 17;
        #pragma unroll
        for (int k = 0; k < 16; k++) atomicAdd(p0 + k, v0[k]);
    }
    __syncthreads();

    if (t < BNODES) {
        int v = b * BNODES + t;
        if (v < N_NODES) {
            float dv = dinv[v];
            const float4* hp = (const float4*)(h1s + (size_t)v * HID);
            float hs[16];
            *(float4*)(hs +  0) = hp[0]; *(float4*)(hs +  4) = hp[1];
            *(float4*)(hs +  8) = hp[2]; *(float4*)(hs + 12) = hp[3];
            float ob[16];
            #pragma unroll
            for (int k = 0; k < 16; k++) {
                float s = acc[t * 17 + k] + hs[k];    /* self loop: h1s already dinv-scaled */
                float val = fmaxf(dv * s + b1s[k], 0.f);
                ob[k] = dv * val;                      /* pre-scale for layer 2 */
            }
            float4* yp = (float4*)(ys + (size_t)v * HID);
            yp[0] = *(float4*)(ob + 0);  yp[1] = *(float4*)(ob + 4);
            yp[2] = *(float4*)(ob + 8);  yp[3] = *(float4*)(ob + 12);
        }
    }
}

/* ---------------- layer-2 aggregate + W2 (16->40) + bias + log_softmax ---------------- */
__global__ __launch_bounds__(512) void k_agg2b(const float* __restrict__ ys,
        const int* __restrict__ gcnt, const int* __restrict__ ebuf,
        const float* __restrict__ dinv, const float* __restrict__ W2,
        const float* __restrict__ b2, float* __restrict__ out) {
    __shared__ float acc[BNODES * 17];
    __shared__ float w2s[HID * NCLS];
    __shared__ float b2s[NCLS];
    int t = threadIdx.x;
    for (int i = t; i < BNODES * 17; i += 512) acc[i] = 0.f;
    for (int i = t; i < HID * NCLS; i += 512) w2s[i] = W2[i];
    if (t < NCLS) b2s[t] = b2[t];
    __syncthreads();

    int b = blockIdx.x;
    int ne = gcnt[b];
    const int* eb = ebuf + b * BCAP;
    int i = t;
    for (; i + 512 < ne; i += 1024) {
        int e0 = eb[i], e1 = eb[i + 512];
        const float4* g0 = (const float4*)(ys + (size_t)(e0 & 0x1FFFF) * HID);
        const float4* g1 = (const float4*)(ys + (size_t)(e1 & 0x1FFFF) * HID);
        float v0[16], v1[16];
        *(float4*)(v0 +  0) = g0[0]; *(float4*)(v0 +  4) = g0[1];
        *(float4*)(v0 +  8) = g0[2]; *(float4*)(v0 + 12) = g0[3];
        *(float4*)(v1 +  0) = g1[0]; *(float4*)(v1 +  4) = g1[1];
        *(float4*)(v1 +  8) = g1[2]; *(float4*)(v1 + 12) = g1[3];
        float* p0 = acc + (e0 >> 17) * 17;
        float* p1 = acc + (e1 >> 17) * 17;
        #pragma unroll
        for (int k = 0; k < 16; k++) atomicAdd(p0 + k, v0[k]);
        #pragma unroll
        for (int k = 0; k < 16; k++) atomicAdd(p1 + k, v1[k]);
    }
    if (i < ne) {
        int e0 = eb[i];
        const float4* g0 = (const float4*)(ys + (size_t)(e0 & 0x1FFFF) * HID);
        float v0[16];
        *(float4*)(v0 +  0) = g0[0]; *(float4*)(v0 +  4) = g0[1];
        *(float4*)(v0 +  8) = g0[2]; *(float4*)(v0 + 12) = g0[3];
        float* p0 = acc + (e0 >> 17) * 17;
        #pragma unroll
        for (int k = 0; k < 16; k++) atomicAdd(p0 + k, v0[k]);
    }
    __syncthreads();

    if (t < BNODES) {
        int v = b * BNODES + t;
        if (v < N_NODES) {
            float dv = dinv[v];
            const float4* sp = (const float4*)(ys + (size_t)v * HID);
            float ss[16];
            *(float4*)(ss +  0) = sp[0]; *(float4*)(ss +  4) = sp[1];
            *(float4*)(ss +  8) = sp[2]; *(float4*)(ss + 12) = sp[3];
            float tv[16];
            #pragma unroll
            for (int k = 0; k < 16; k++) tv[k] = dv * (acc[t * 17 + k] + ss[k]);

            float lg[NCLS];
            #pragma unroll
            for (int c = 0; c < NCLS; c++) lg[c] = b2s[c];
            #pragma unroll
            for (int k = 0; k < HID; k++) {
                float tk = tv[k];
                #pragma unroll
                for (int c = 0; c < NCLS; c++) lg[c] = fmaf(tk, w2s[k * NCLS + c], lg[c]);
            }
            float mx = lg[0];
            #pragma unroll
            for (int c = 1; c < NCLS; c++) mx = fmaxf(mx, lg[c]);
            float sum = 0.f;
            #pragma unroll
            for (int c = 0; c < NCLS; c++) sum += __expf(lg[c] - mx);
            float lse = mx + __logf(sum);

            float4* op = (float4*)(out + (size_t)v * NCLS);
            #pragma unroll
            for (int q = 0; q < 10; q++) {
                float4 o;
                o.x = lg[q * 4 + 0] - lse;
                o.y = lg[q * 4 + 1] - lse;
                o.z = lg[q * 4 + 2] - lse;
                o.w = lg[q * 4 + 3] - lse;
                op[q] = o;
            }
        }
    }
}

extern "C" void kernel_launch(void* const* d_in, const int* in_sizes, int n_in,
                              void* d_out, int out_size, void* d_ws, size_t ws_size,
                              hipStream_t stream) {
    const float* x  = (const float*)d_in[0];
    const int*   ei = (const int*)d_in[1];
    const float* W1 = (const float*)d_in[2];
    const float* b1 = (const float*)d_in[3];
    const float* W2 = (const float*)d_in[4];
    const float* b2 = (const float*)d_in[5];
    float* out = (float*)d_out;
    const int* src = ei;
    const int* dst = ei + NEDGE;

    char* w = (char*)d_ws;
    size_t o = 0;
    auto alloc = [&](size_t bytes) -> char* {
        char* p = w + o;
        o += (bytes + 511) & ~(size_t)511;
        return p;
    };
    int*   gcnt = (int*)alloc((size_t)NBUCK * 4);
    int*   ebuf = (int*)alloc((size_t)NBUCK * BCAP * 4);   /* 13.8 MB */
    float* dinv = (float*)alloc((size_t)N_NODES * 4);
    float* h1s  = (float*)alloc((size_t)N_NODES * HID * 4);
    float* ys   = (float*)alloc((size_t)N_NODES * HID * 4);
    /* total ~26.9 MB, under the previously-proven 27.2 MB footprint */

    hipMemsetAsync(gcnt, 0, (size_t)NBUCK * 4, stream);

    k_part <<<NPART, 256, 0, stream>>>(src, dst, gcnt, ebuf);
    k_bdeg <<<NBUCK, 256, 0, stream>>>(gcnt, ebuf, dinv);
    k_gemm1<<<(N_NODES + 63) / 64, 256, 0, stream>>>(x, W1, dinv, h1s);
    k_agg1b<<<NBUCK, 512, 0, stream>>>(h1s, gcnt, ebuf, dinv, b1, ys);
    k_agg2b<<<NBUCK, 512, 0, stream>>>(ys, gcnt, ebuf, dinv, W2, b2, out);
}

// Round 3
// 999.196 us; speedup vs baseline: 1.0596x; 1.0596x over previous
//
#include <hip/hip_runtime.h>

#define N_NODES 100000
#define NEDGE   3200000
#define F_IN    512
#define HID     16
#define NCLS    40

/* ---- dst-bucket partition geometry ---- */
#define BSHIFT  8
#define BNODES  256                                  /* nodes per bucket */
#define NBUCK   ((N_NODES + BNODES - 1) / BNODES)    /* 391 */
#define NPAD    (NBUCK * BNODES)                     /* 100096 padded nodes */
#define BCAP    8832    /* mean 8192, sd ~90 -> +7 sigma */
#define EPB     5120    /* edges per partition block: 256 thr x 4 x 5 */
#define NPART   (NEDGE / EPB)                        /* 625, exact */
#define SSUB    4       /* sub-blocks per bucket in aggregation */

typedef __bf16 bf16x8 __attribute__((ext_vector_type(8)));
typedef float floatx4 __attribute__((ext_vector_type(4)));

/* ---------------- edge partition by dst bucket ---------------- */
__global__ __launch_bounds__(256) void k_part(const int* __restrict__ src,
                                              const int* __restrict__ dst,
                                              int* __restrict__ gcnt,
                                              int* __restrict__ ebuf) {
    __shared__ int hist[NBUCK];
    int t = threadIdx.x;
    for (int i = t; i < NBUCK; i += 256) hist[i] = 0;
    __syncthreads();

    int base = blockIdx.x * EPB + t * 4;
    int4 dr[5];
    #pragma unroll
    for (int s = 0; s < 5; s++) {
        dr[s] = *(const int4*)(dst + base + s * 1024);
        atomicAdd(&hist[dr[s].x >> BSHIFT], 1);
        atomicAdd(&hist[dr[s].y >> BSHIFT], 1);
        atomicAdd(&hist[dr[s].z >> BSHIFT], 1);
        atomicAdd(&hist[dr[s].w >> BSHIFT], 1);
    }
    __syncthreads();

    for (int i = t; i < NBUCK; i += 256) {
        int h = hist[i];
        hist[i] = h ? atomicAdd(&gcnt[i], h) : 0;
    }
    __syncthreads();

    #pragma unroll
    for (int s = 0; s < 5; s++) {
        int4 s4 = *(const int4*)(src + base + s * 1024);
        int dd[4] = {dr[s].x, dr[s].y, dr[s].z, dr[s].w};
        int ss[4] = {s4.x, s4.y, s4.z, s4.w};
        #pragma unroll
        for (int j = 0; j < 4; j++) {
            int d = dd[j];
            int b = d >> BSHIFT;
            int p = atomicAdd(&hist[b], 1);
            ebuf[b * BCAP + p] = ((d & (BNODES - 1)) << 17) | ss[j];
        }
    }
}

/* ---------------- per-bucket degree -> dinv ---------------- */
__global__ __launch_bounds__(256) void k_bdeg(const int* __restrict__ gcnt,
                                              const int* __restrict__ ebuf,
                                              float* __restrict__ dinv) {
    __shared__ int cnt[BNODES];
    int b = blockIdx.x, t = threadIdx.x;
    cnt[t] = 0;
    __syncthreads();
    int ne = gcnt[b];
    const int* e = ebuf + b * BCAP;
    for (int i = t; i < ne; i += 256) atomicAdd(&cnt[e[i] >> 17], 1);
    __syncthreads();
    int v = b * BNODES + t;
    if (v < N_NODES) dinv[v] = rsqrtf((float)(cnt[t] + 1));
}

/* ---------------- GEMM1: h1s = dinv * (x @ W1) ---------------- */
__global__ __launch_bounds__(256) void k_gemm1(const float* __restrict__ x,
                                               const float* __restrict__ W1,
                                               const float* __restrict__ dinv,
                                               float* __restrict__ h1s) {
    __shared__ __bf16 wh[16 * 64 * 8];
    __shared__ __bf16 wl[16 * 64 * 8];
    int t = threadIdx.x;
    for (int e = t; e < 8192; e += 256) {
        int c = e >> 9, l = (e >> 3) & 63, j = e & 7;
        int k = c * 32 + ((l >> 4) << 3) + j;
        int n = l & 15;
        float wv = W1[k * HID + n];
        __bf16 h = (__bf16)wv;
        wh[e] = h;
        wl[e] = (__bf16)(wv - (float)h);
    }
    __syncthreads();

    int wave = t >> 6, lane = t & 63;
    int q = lane >> 4, m = lane & 15;
    int row0 = blockIdx.x * 64 + wave * 16;
    int rowa = row0 + m;
    if (rowa >= N_NODES) rowa = N_NODES - 1;
    const float* xr = x + (size_t)rowa * F_IN + q * 8;

    floatx4 acc = {0.f, 0.f, 0.f, 0.f};
    #pragma unroll 4
    for (int c = 0; c < 16; c++) {
        float4 a0 = *(const float4*)(xr + c * 32);
        float4 a1 = *(const float4*)(xr + c * 32 + 4);
        float xv[8] = {a0.x, a0.y, a0.z, a0.w, a1.x, a1.y, a1.z, a1.w};
        bf16x8 ah, al;
        #pragma unroll
        for (int j = 0; j < 8; j++) {
            __bf16 h = (__bf16)xv[j];
            ah[j] = h;
            al[j] = (__bf16)(xv[j] - (float)h);
        }
        bf16x8 bh = *(const bf16x8*)&wh[(c * 64 + lane) * 8];
        bf16x8 bl = *(const bf16x8*)&wl[(c * 64 + lane) * 8];
        acc = __builtin_amdgcn_mfma_f32_16x16x32_bf16(ah, bh, acc, 0, 0, 0);
        acc = __builtin_amdgcn_mfma_f32_16x16x32_bf16(ah, bl, acc, 0, 0, 0);
        acc = __builtin_amdgcn_mfma_f32_16x16x32_bf16(al, bh, acc, 0, 0, 0);
    }
    #pragma unroll
    for (int r = 0; r < 4; r++) {
        int grow = row0 + q * 4 + r;
        if (grow < N_NODES) h1s[grow * HID + (lane & 15)] = dinv[grow] * acc[r];
    }
}

/* ---------------- aggregation core: 4 sub-blocks per bucket ----------------
 * Edge-quad gather: 4 lanes handle one edge (lane j loads 16B at offset j*16)
 * -> a wave's gather touches 16 cache lines, not 64. LDS acc (stride 17),
 * merged into the global accumulator with coalesced atomics. */
__device__ __forceinline__ void agg_core(const float* __restrict__ feat,
                                         const int* __restrict__ gcnt,
                                         const int* __restrict__ ebuf,
                                         float* __restrict__ gacc) {
    __shared__ float acc[BNODES * 17];
    int t = threadIdx.x;
    for (int i = t; i < BNODES * 17; i += 512) acc[i] = 0.f;
    __syncthreads();

    int b = blockIdx.x >> 2, s = blockIdx.x & (SSUB - 1);
    int ne = gcnt[b];
    const int* eb = ebuf + b * BCAP;
    int j4 = (t & 3) * 4;
    int g = s * 128 + (t >> 2);          /* edge slot; block round = 512 edges */

    for (; g + 1536 < ne; g += 2048) {   /* unroll 4: edges g, +512, +1024, +1536 */
        int e0 = eb[g], e1 = eb[g + 512], e2 = eb[g + 1024], e3 = eb[g + 1536];
        float4 v0 = *(const float4*)(feat + (size_t)(e0 & 0x1FFFF) * HID + j4);
        float4 v1 = *(const float4*)(feat + (size_t)(e1 & 0x1FFFF) * HID + j4);
        float4 v2 = *(const float4*)(feat + (size_t)(e2 & 0x1FFFF) * HID + j4);
        float4 v3 = *(const float4*)(feat + (size_t)(e3 & 0x1FFFF) * HID + j4);
        float* p0 = acc + (e0 >> 17) * 17 + j4;
        float* p1 = acc + (e1 >> 17) * 17 + j4;
        float* p2 = acc + (e2 >> 17) * 17 + j4;
        float* p3 = acc + (e3 >> 17) * 17 + j4;
        atomicAdd(p0 + 0, v0.x); atomicAdd(p0 + 1, v0.y);
        atomicAdd(p0 + 2, v0.z); atomicAdd(p0 + 3, v0.w);
        atomicAdd(p1 + 0, v1.x); atomicAdd(p1 + 1, v1.y);
        atomicAdd(p1 + 2, v1.z); atomicAdd(p1 + 3, v1.w);
        atomicAdd(p2 + 0, v2.x); atomicAdd(p2 + 1, v2.y);
        atomicAdd(p2 + 2, v2.z); atomicAdd(p2 + 3, v2.w);
        atomicAdd(p3 + 0, v3.x); atomicAdd(p3 + 1, v3.y);
        atomicAdd(p3 + 2, v3.z); atomicAdd(p3 + 3, v3.w);
    }
    for (; g < ne; g += 512) {
        int e = eb[g];
        float4 v = *(const float4*)(feat + (size_t)(e & 0x1FFFF) * HID + j4);
        float* p = acc + (e >> 17) * 17 + j4;
        atomicAdd(p + 0, v.x); atomicAdd(p + 1, v.y);
        atomicAdd(p + 2, v.z); atomicAdd(p + 3, v.w);
    }
    __syncthreads();

    /* coalesced merge: 4096 floats per bucket region */
    int base = b * (BNODES * HID);
    #pragma unroll
    for (int r = 0; r < 8; r++) {
        int f = t + 512 * r;
        float vv = acc[(f >> 4) * 17 + (f & 15)];
        if (vv != 0.f) atomicAdd(&gacc[base + f], vv);
    }
}

__global__ __launch_bounds__(512) void k_agg1c(const float* __restrict__ h1s,
        const int* __restrict__ gcnt, const int* __restrict__ ebuf,
        float* __restrict__ ys) {
    agg_core(h1s, gcnt, ebuf, ys);
}

__global__ __launch_bounds__(512) void k_agg2c(const float* __restrict__ ys,
        const int* __restrict__ gcnt, const int* __restrict__ ebuf,
        float* __restrict__ hacc) {
    agg_core(ys, gcnt, ebuf, hacc);
}

/* ---------------- epilogue 1: ys = dinv * relu(dinv*(acc+self) + b1), in place ---------------- */
__global__ __launch_bounds__(256) void k_ep1(float* __restrict__ ys,
        const float* __restrict__ h1s, const float* __restrict__ dinv,
        const float* __restrict__ b1) {
    int v = blockIdx.x * 256 + threadIdx.x;
    if (v >= N_NODES) return;
    float dv = dinv[v];
    const float4* ap = (const float4*)(ys + (size_t)v * HID);
    const float4* hp = (const float4*)(h1s + (size_t)v * HID);
    float a[16], h[16];
    *(float4*)(a + 0) = ap[0]; *(float4*)(a + 4) = ap[1];
    *(float4*)(a + 8) = ap[2]; *(float4*)(a + 12) = ap[3];
    *(float4*)(h + 0) = hp[0]; *(float4*)(h + 4) = hp[1];
    *(float4*)(h + 8) = hp[2]; *(float4*)(h + 12) = hp[3];
    float ob[16];
    #pragma unroll
    for (int k = 0; k < 16; k++) {
        float s = a[k] + h[k];                 /* self loop: h1s already dinv-scaled */
        float val = fmaxf(dv * s + b1[k], 0.f);
        ob[k] = dv * val;                      /* pre-scale for layer 2 */
    }
    float4* yp = (float4*)(ys + (size_t)v * HID);
    yp[0] = *(float4*)(ob + 0);  yp[1] = *(float4*)(ob + 4);
    yp[2] = *(float4*)(ob + 8);  yp[3] = *(float4*)(ob + 12);
}

/* ---------------- epilogue 2: W2 (16->40) + bias + log_softmax ---------------- */
__global__ __launch_bounds__(256) void k_ep2(const float* __restrict__ hacc,
        const float* __restrict__ ys, const float* __restrict__ dinv,
        const float* __restrict__ W2, const float* __restrict__ b2,
        float* __restrict__ out) {
    __shared__ float w2s[HID * NCLS];
    int t = threadIdx.x;
    for (int i = t; i < HID * NCLS; i += 256) w2s[i] = W2[i];
    __syncthreads();
    int v = blockIdx.x * 256 + t;
    if (v >= N_NODES) return;
    float dv = dinv[v];
    const float4* ap = (const float4*)(hacc + (size_t)v * HID);
    const float4* sp = (const float4*)(ys + (size_t)v * HID);
    float a[16], ss[16];
    *(float4*)(a + 0) = ap[0]; *(float4*)(a + 4) = ap[1];
    *(float4*)(a + 8) = ap[2]; *(float4*)(a + 12) = ap[3];
    *(float4*)(ss + 0) = sp[0]; *(float4*)(ss + 4) = sp[1];
    *(float4*)(ss + 8) = sp[2]; *(float4*)(ss + 12) = sp[3];
    float tv[16];
    #pragma unroll
    for (int k = 0; k < 16; k++) tv[k] = dv * (a[k] + ss[k]);

    float lg[NCLS];
    #pragma unroll
    for (int c = 0; c < NCLS; c++) lg[c] = b2[c];
    #pragma unroll
    for (int k = 0; k < HID; k++) {
        float tk = tv[k];
        #pragma unroll
        for (int c = 0; c < NCLS; c++) lg[c] = fmaf(tk, w2s[k * NCLS + c], lg[c]);
    }
    float mx = lg[0];
    #pragma unroll
    for (int c = 1; c < NCLS; c++) mx = fmaxf(mx, lg[c]);
    float sum = 0.f;
    #pragma unroll
    for (int c = 0; c < NCLS; c++) sum += __expf(lg[c] - mx);
    float lse = mx + __logf(sum);

    float4* op = (float4*)(out + (size_t)v * NCLS);
    #pragma unroll
    for (int q = 0; q < 10; q++) {
        float4 o;
        o.x = lg[q * 4 + 0] - lse;
        o.y = lg[q * 4 + 1] - lse;
        o.z = lg[q * 4 + 2] - lse;
        o.w = lg[q * 4 + 3] - lse;
        op[q] = o;
    }
}

extern "C" void kernel_launch(void* const* d_in, const int* in_sizes, int n_in,
                              void* d_out, int out_size, void* d_ws, size_t ws_size,
                              hipStream_t stream) {
    const float* x  = (const float*)d_in[0];
    const int*   ei = (const int*)d_in[1];
    const float* W1 = (const float*)d_in[2];
    const float* b1 = (const float*)d_in[3];
    const float* W2 = (const float*)d_in[4];
    const float* b2 = (const float*)d_in[5];
    float* out = (float*)d_out;
    const int* src = ei;
    const int* dst = ei + NEDGE;

    char* w = (char*)d_ws;
    size_t o = 0;
    auto alloc = [&](size_t bytes) -> char* {
        char* p = w + o;
        o += (bytes + 511) & ~(size_t)511;
        return p;
    };
    int*   gcnt = (int*)alloc((size_t)NBUCK * 4);
    int*   ebuf = (int*)alloc((size_t)NBUCK * BCAP * 4);   /* 13.8 MB */
    float* dinv = (float*)alloc((size_t)N_NODES * 4);
    float* h1s  = (float*)alloc((size_t)NPAD * HID * 4);   /* padded to bucket grid */
    float* ys   = (float*)alloc((size_t)NPAD * HID * 4);
    /* total ~27.03 MB, under the previously-proven 27.2 MB footprint */

    hipMemsetAsync(gcnt, 0, (size_t)NBUCK * 4, stream);

    k_part <<<NPART, 256, 0, stream>>>(src, dst, gcnt, ebuf);
    k_bdeg <<<NBUCK, 256, 0, stream>>>(gcnt, ebuf, dinv);
    k_gemm1<<<(N_NODES + 63) / 64, 256, 0, stream>>>(x, W1, dinv, h1s);

    hipMemsetAsync(ys, 0, (size_t)NPAD * HID * 4, stream);
    k_agg1c<<<NBUCK * SSUB, 512, 0, stream>>>(h1s, gcnt, ebuf, ys);
    k_ep1  <<<NBUCK, 256, 0, stream>>>(ys, h1s, dinv, b1);

    hipMemsetAsync(h1s, 0, (size_t)NPAD * HID * 4, stream);
    k_agg2c<<<NBUCK * SSUB, 512, 0, stream>>>(ys, gcnt, ebuf, h1s);
    k_ep2  <<<NBUCK, 256, 0, stream>>>(h1s, ys, dinv, W2, b2, out);
}

// Round 6
// 479.928 us; speedup vs baseline: 2.2060x; 2.0820x over previous
//
#include <hip/hip_runtime.h>

#define N_NODES 100000
#define NEDGE   3200000
#define F_IN    512
#define HID     16
#define NCLS    40

/* ---- dst-bucket partition geometry ---- */
#define BSHIFT  8
#define BNODES  256                                  /* nodes per bucket */
#define NBUCK   ((N_NODES + BNODES - 1) / BNODES)    /* 391 */
#define BCAP    8832    /* mean 8192, sd ~90 -> +7 sigma */
#define EPB     5120    /* edges per partition block: 256 thr x 4 x 5 */
#define NPART   (NEDGE / EPB)                        /* 625, exact */

typedef __bf16 bf16x8 __attribute__((ext_vector_type(8)));
typedef float floatx4 __attribute__((ext_vector_type(4)));

/* ---------------- edge partition by dst bucket ----------------
 * (byte-identical to the round-2/3 proven kernel)
 * Per block: LDS histogram over 391 buckets, ONE global atomic per
 * (block,bucket) to reserve a run, then append-scatter packed entries
 * (ldst<<17 | src) into the bucket region. */
__global__ __launch_bounds__(256) void k_part(const int* __restrict__ src,
                                              const int* __restrict__ dst,
                                              int* __restrict__ gcnt,
                                              int* __restrict__ ebuf) {
    __shared__ int hist[NBUCK];
    int t = threadIdx.x;
    for (int i = t; i < NBUCK; i += 256) hist[i] = 0;
    __syncthreads();

    int base = blockIdx.x * EPB + t * 4;
    int4 dr[5];
    #pragma unroll
    for (int s = 0; s < 5; s++) {
        dr[s] = *(const int4*)(dst + base + s * 1024);
        atomicAdd(&hist[dr[s].x >> BSHIFT], 1);
        atomicAdd(&hist[dr[s].y >> BSHIFT], 1);
        atomicAdd(&hist[dr[s].z >> BSHIFT], 1);
        atomicAdd(&hist[dr[s].w >> BSHIFT], 1);
    }
    __syncthreads();

    for (int i = t; i < NBUCK; i += 256) {
        int h = hist[i];
        hist[i] = h ? atomicAdd(&gcnt[i], h) : 0;
    }
    __syncthreads();

    #pragma unroll
    for (int s = 0; s < 5; s++) {
        int4 s4 = *(const int4*)(src + base + s * 1024);
        int dd[4] = {dr[s].x, dr[s].y, dr[s].z, dr[s].w};
        int ss[4] = {s4.x, s4.y, s4.z, s4.w};
        #pragma unroll
        for (int j = 0; j < 4; j++) {
            int d = dd[j];
            int b = d >> BSHIFT;
            int p = atomicAdd(&hist[b], 1);
            if (p < BCAP) ebuf[b * BCAP + p] = ((d & (BNODES - 1)) << 17) | ss[j];
        }
    }
}

/* ---------------- per-bucket counting sort -> dense CSR (OUT-OF-PLACE) ----------------
 * One block per bucket: dense global base = sum gcnt[0..b) (strided sum +
 * LDS reduce), stage bucket edges in LDS, 256-bin histogram (= degree),
 * Hillis-Steele prefix, scatter src ids into dense col[] sorted by dst.
 * Emits rinfo[v] = (deg<<22) | dense_start (dense_start < 3.2M < 2^22). */
__global__ __launch_bounds__(256) void k_sortb(const int* __restrict__ gcnt,
                                               const int* __restrict__ ebuf,
                                               int* __restrict__ col,
                                               int* __restrict__ rinfo) {
    __shared__ int ed[BCAP];
    __shared__ int cnt[BNODES];
    __shared__ int pref[BNODES];
    int b = blockIdx.x, t = threadIdx.x;

    /* dense exclusive prefix of gcnt over buckets [0, b) */
    int partial = 0;
    for (int i = t; i < b; i += 256) partial += gcnt[i];
    pref[t] = partial;
    __syncthreads();
    for (int off = 128; off; off >>= 1) {
        if (t < off) pref[t] += pref[t + off];
        __syncthreads();
    }
    int gbase = pref[0];
    __syncthreads();

    int ne = gcnt[b];
    if (ne > BCAP) ne = BCAP;
    cnt[t] = 0;
    __syncthreads();
    for (int i = t; i < ne; i += 256) {
        int e = ebuf[b * BCAP + i];
        ed[i] = e;
        atomicAdd(&cnt[e >> 17], 1);
    }
    __syncthreads();
    int c = cnt[t];
    pref[t] = c;
    __syncthreads();
    for (int off = 1; off < 256; off <<= 1) {
        int add = (t >= off) ? pref[t - off] : 0;
        __syncthreads();
        pref[t] += add;
        __syncthreads();
    }
    int start = pref[t] - c;               /* exclusive prefix within bucket */
    int v = b * BNODES + t;
    if (v < N_NODES) rinfo[v] = (c << 22) | (gbase + start);
    cnt[t] = start;                        /* reuse as local cursor */
    __syncthreads();
    for (int i = t; i < ne; i += 256) {
        int e = ed[i];
        int pos = atomicAdd(&cnt[e >> 17], 1);
        col[gbase + pos] = e & 0x1FFFF;    /* plain src id, dst-sorted */
    }
}

/* ---------------- GEMM1: h1s = dinv * (x @ W1), bf16 MFMA hi/lo split ---------------- */
__global__ __launch_bounds__(256) void k_gemm1(const float* __restrict__ x,
                                               const float* __restrict__ W1,
                                               const int* __restrict__ rinfo,
                                               float* __restrict__ h1s) {
    __shared__ __bf16 wh[16 * 64 * 8];
    __shared__ __bf16 wl[16 * 64 * 8];
    int t = threadIdx.x;
    for (int e = t; e < 8192; e += 256) {
        int c = e >> 9, l = (e >> 3) & 63, j = e & 7;
        int k = c * 32 + ((l >> 4) << 3) + j;
        int n = l & 15;
        float wv = W1[k * HID + n];
        __bf16 h = (__bf16)wv;
        wh[e] = h;
        wl[e] = (__bf16)(wv - (float)h);
    }
    __syncthreads();

    int wave = t >> 6, lane = t & 63;
    int q = lane >> 4, m = lane & 15;
    int row0 = blockIdx.x * 64 + wave * 16;
    int rowa = row0 + m;
    if (rowa >= N_NODES) rowa = N_NODES - 1;
    const float* xr = x + (size_t)rowa * F_IN + q * 8;

    floatx4 acc = {0.f, 0.f, 0.f, 0.f};
    #pragma unroll 4
    for (int c = 0; c < 16; c++) {
        float4 a0 = *(const float4*)(xr + c * 32);
        float4 a1 = *(const float4*)(xr + c * 32 + 4);
        float xv[8] = {a0.x, a0.y, a0.z, a0.w, a1.x, a1.y, a1.z, a1.w};
        bf16x8 ah, al;
        #pragma unroll
        for (int j = 0; j < 8; j++) {
            __bf16 h = (__bf16)xv[j];
            ah[j] = h;
            al[j] = (__bf16)(xv[j] - (float)h);
        }
        bf16x8 bh = *(const bf16x8*)&wh[(c * 64 + lane) * 8];
        bf16x8 bl = *(const bf16x8*)&wl[(c * 64 + lane) * 8];
        acc = __builtin_amdgcn_mfma_f32_16x16x32_bf16(ah, bh, acc, 0, 0, 0);
        acc = __builtin_amdgcn_mfma_f32_16x16x32_bf16(ah, bl, acc, 0, 0, 0);
        acc = __builtin_amdgcn_mfma_f32_16x16x32_bf16(al, bh, acc, 0, 0, 0);
    }
    #pragma unroll
    for (int r = 0; r < 4; r++) {
        int grow = row0 + q * 4 + r;
        if (grow < N_NODES) {
            float dv = rsqrtf((float)(((rinfo[grow] >> 22) & 0x3FF) + 1));
            h1s[grow * HID + (lane & 15)] = dv * acc[r];
        }
    }
}

/* ---------------- layer-1 aggregate, node-parallel CSR walk ----------------
 * thread g=(v,k): 16 lanes of a group read h1s[c*16+k] -> ONE 64B line per
 * edge, fully consumed; col index is a 16-lane broadcast. Unroll 4 with
 * independent accumulators for MLP. Fused bias+relu+dinv epilogue. */
__global__ __launch_bounds__(256) void k_agg1(const float* __restrict__ h1s,
        const int* __restrict__ rinfo, const int* __restrict__ col,
        const float* __restrict__ b1, float* __restrict__ ys) {
    int g = blockIdx.x * 256 + threadIdx.x;   /* grid == N*16 exactly */
    int v = g >> 4, k = g & 15;
    int ri = rinfo[v];
    int beg = ri & 0x3FFFFF;
    int deg = (ri >> 22) & 0x3FF;             /* mask: hang-proof the loop bound */
    int end = beg + deg;
    float s0 = 0.f, s1 = 0.f, s2 = 0.f, s3 = 0.f;
    int j = beg;
    for (; j + 3 < end; j += 4) {
        int c0 = col[j], c1 = col[j + 1], c2 = col[j + 2], c3 = col[j + 3];
        s0 += h1s[c0 * HID + k];
        s1 += h1s[c1 * HID + k];
        s2 += h1s[c2 * HID + k];
        s3 += h1s[c3 * HID + k];
    }
    for (; j < end; j++) s0 += h1s[col[j] * HID + k];
    float sum = (s0 + s1) + (s2 + s3) + h1s[v * HID + k];  /* self loop */
    float dv = rsqrtf((float)(deg + 1));
    float val = fmaxf(dv * sum + b1[k], 0.f);
    ys[v * HID + k] = dv * val;               /* pre-scale for layer 2 */
}

/* ---------------- layer-2 aggregate + W2 (16->40) + bias + log_softmax ---------------- */
__global__ __launch_bounds__(256) void k_agg2(const float* __restrict__ ys,
        const int* __restrict__ rinfo, const int* __restrict__ col,
        const float* __restrict__ W2, const float* __restrict__ b2,
        float* __restrict__ out) {
    __shared__ float w2s[HID * NCLS];
    __shared__ float b2s[NCLS];
    int t = threadIdx.x;
    for (int i = t; i < HID * NCLS; i += 256) w2s[i] = W2[i];
    if (t < NCLS) b2s[t] = b2[t];
    __syncthreads();

    int g = blockIdx.x * 256 + t;             /* grid == N*16 exactly */
    int v = g >> 4, l = g & 15;
    int ri = rinfo[v];
    int beg = ri & 0x3FFFFF;
    int deg = (ri >> 22) & 0x3FF;
    int end = beg + deg;
    float s0 = 0.f, s1 = 0.f, s2 = 0.f, s3 = 0.f;
    int j = beg;
    for (; j + 3 < end; j += 4) {
        int c0 = col[j], c1 = col[j + 1], c2 = col[j + 2], c3 = col[j + 3];
        s0 += ys[c0 * HID + l];
        s1 += ys[c1 * HID + l];
        s2 += ys[c2 * HID + l];
        s3 += ys[c3 * HID + l];
    }
    for (; j < end; j++) s0 += ys[col[j] * HID + l];
    float dv = rsqrtf((float)(deg + 1));
    float tval = dv * ((s0 + s1) + (s2 + s3) + ys[v * HID + l]);

    /* 16->40 matvec: lane l covers classes {l, l+16, l+32(l<8)} */
    float acc0 = 0.f, acc1 = 0.f, acc2 = 0.f;
    #pragma unroll
    for (int k = 0; k < 16; k++) {
        float tk = __shfl(tval, k, 16);
        acc0 = fmaf(tk, w2s[k * NCLS + l], acc0);
        acc1 = fmaf(tk, w2s[k * NCLS + l + 16], acc1);
        if (l < 8) acc2 = fmaf(tk, w2s[k * NCLS + l + 32], acc2);
    }
    acc0 += b2s[l];
    acc1 += b2s[l + 16];
    float acc2b = (l < 8) ? (acc2 + b2s[l + 32]) : -1e30f;

    float mx = fmaxf(fmaxf(acc0, acc1), acc2b);
    for (int off = 8; off; off >>= 1) mx = fmaxf(mx, __shfl_xor(mx, off, 16));
    float s = __expf(acc0 - mx) + __expf(acc1 - mx) + __expf(acc2b - mx);
    for (int off = 8; off; off >>= 1) s += __shfl_xor(s, off, 16);
    float lse = mx + __logf(s);

    out[v * NCLS + l] = acc0 - lse;
    out[v * NCLS + l + 16] = acc1 - lse;
    if (l < 8) out[v * NCLS + l + 32] = acc2b - lse;
}

extern "C" void kernel_launch(void* const* d_in, const int* in_sizes, int n_in,
                              void* d_out, int out_size, void* d_ws, size_t ws_size,
                              hipStream_t stream) {
    const float* x  = (const float*)d_in[0];
    const int*   ei = (const int*)d_in[1];
    const float* W1 = (const float*)d_in[2];
    const float* b1 = (const float*)d_in[3];
    const float* W2 = (const float*)d_in[4];
    const float* b2 = (const float*)d_in[5];
    float* out = (float*)d_out;
    const int* src = ei;
    const int* dst = ei + NEDGE;

    char* w = (char*)d_ws;
    size_t o = 0;
    auto alloc = [&](size_t bytes) -> char* {
        char* p = w + o;
        o += (bytes + 511) & ~(size_t)511;
        return p;
    };
    int*   gcnt  = (int*)alloc((size_t)NBUCK * 4);
    int*   rinfo = (int*)alloc((size_t)N_NODES * 4);
    int*   col   = (int*)alloc((size_t)NEDGE * 4);          /* 12.8 MB dense CSR */
    /* union: ebuf (13.8 MB, dead after k_sortb) overlaps h1s+ys (12.8 MB,
     * first written by k_gemm1 which runs after k_sortb — stream ordered) */
    char*  uni   = alloc((size_t)NBUCK * BCAP * 4);
    int*   ebuf  = (int*)uni;
    float* h1s   = (float*)uni;
    float* ys    = h1s + (size_t)N_NODES * HID;
    /* total ~27.02 MB <= proven 27.03 MB */

    hipMemsetAsync(gcnt, 0, (size_t)NBUCK * 4, stream);

    k_part <<<NPART, 256, 0, stream>>>(src, dst, gcnt, ebuf);
    k_sortb<<<NBUCK, 256, 0, stream>>>(gcnt, ebuf, col, rinfo);
    k_gemm1<<<(N_NODES + 63) / 64, 256, 0, stream>>>(x, W1, rinfo, h1s);
    k_agg1 <<<(N_NODES * HID) / 256, 256, 0, stream>>>(h1s, rinfo, col, b1, ys);
    k_agg2 <<<(N_NODES * HID) / 256, 256, 0, stream>>>(ys, rinfo, col, W2, b2, out);
}

// Round 7
// 455.562 us; speedup vs baseline: 2.3240x; 1.0535x over previous
//
#include <hip/hip_runtime.h>

#define N_NODES 100000
#define NEDGE   3200000
#define F_IN    512
#define HID     16
#define NCLS    40

/* ---- dst-bucket partition geometry ---- */
#define BSHIFT  8
#define BNODES  256                                  /* nodes per bucket */
#define NBUCK   ((N_NODES + BNODES - 1) / BNODES)    /* 391 */
#define BCAP    8832    /* mean 8192, sd ~90 -> +7 sigma */
#define EPB     5120    /* edges per partition block: 256 thr x 4 x 5 */
#define NPART   (NEDGE / EPB)                        /* 625, exact */

typedef __bf16 bf16x8 __attribute__((ext_vector_type(8)));
typedef float floatx4 __attribute__((ext_vector_type(4)));

/* ---------------- edge partition by dst bucket (proven r6) ---------------- */
__global__ __launch_bounds__(256) void k_part(const int* __restrict__ src,
                                              const int* __restrict__ dst,
                                              int* __restrict__ gcnt,
                                              int* __restrict__ ebuf) {
    __shared__ int hist[NBUCK];
    int t = threadIdx.x;
    for (int i = t; i < NBUCK; i += 256) hist[i] = 0;
    __syncthreads();

    int base = blockIdx.x * EPB + t * 4;
    int4 dr[5];
    #pragma unroll
    for (int s = 0; s < 5; s++) {
        dr[s] = *(const int4*)(dst + base + s * 1024);
        atomicAdd(&hist[dr[s].x >> BSHIFT], 1);
        atomicAdd(&hist[dr[s].y >> BSHIFT], 1);
        atomicAdd(&hist[dr[s].z >> BSHIFT], 1);
        atomicAdd(&hist[dr[s].w >> BSHIFT], 1);
    }
    __syncthreads();

    for (int i = t; i < NBUCK; i += 256) {
        int h = hist[i];
        hist[i] = h ? atomicAdd(&gcnt[i], h) : 0;
    }
    __syncthreads();

    #pragma unroll
    for (int s = 0; s < 5; s++) {
        int4 s4 = *(const int4*)(src + base + s * 1024);
        int dd[4] = {dr[s].x, dr[s].y, dr[s].z, dr[s].w};
        int ss[4] = {s4.x, s4.y, s4.z, s4.w};
        #pragma unroll
        for (int j = 0; j < 4; j++) {
            int d = dd[j];
            int b = d >> BSHIFT;
            int p = atomicAdd(&hist[b], 1);
            if (p < BCAP) ebuf[b * BCAP + p] = ((d & (BNODES - 1)) << 17) | ss[j];
        }
    }
}

/* ---------------- per-bucket counting sort -> dense CSR (proven r6) ---------------- */
__global__ __launch_bounds__(256) void k_sortb(const int* __restrict__ gcnt,
                                               const int* __restrict__ ebuf,
                                               int* __restrict__ col,
                                               int* __restrict__ rinfo) {
    __shared__ int ed[BCAP];
    __shared__ int cnt[BNODES];
    __shared__ int pref[BNODES];
    int b = blockIdx.x, t = threadIdx.x;

    /* dense exclusive prefix of gcnt over buckets [0, b) */
    int partial = 0;
    for (int i = t; i < b; i += 256) partial += gcnt[i];
    pref[t] = partial;
    __syncthreads();
    for (int off = 128; off; off >>= 1) {
        if (t < off) pref[t] += pref[t + off];
        __syncthreads();
    }
    int gbase = pref[0];
    __syncthreads();

    int ne = gcnt[b];
    if (ne > BCAP) ne = BCAP;
    cnt[t] = 0;
    __syncthreads();
    for (int i = t; i < ne; i += 256) {
        int e = ebuf[b * BCAP + i];
        ed[i] = e;
        atomicAdd(&cnt[e >> 17], 1);
    }
    __syncthreads();
    int c = cnt[t];
    pref[t] = c;
    __syncthreads();
    for (int off = 1; off < 256; off <<= 1) {
        int add = (t >= off) ? pref[t - off] : 0;
        __syncthreads();
        pref[t] += add;
        __syncthreads();
    }
    int start = pref[t] - c;
    int v = b * BNODES + t;
    if (v < N_NODES) rinfo[v] = (c << 22) | (gbase + start);
    cnt[t] = start;
    __syncthreads();
    for (int i = t; i < ne; i += 256) {
        int e = ed[i];
        int pos = atomicAdd(&cnt[e >> 17], 1);
        col[gbase + pos] = e & 0x1FFFF;
    }
}

/* ---------------- GEMM1: h1s(fp16) = dinv * (x @ W1), bf16 MFMA hi/lo split ----------------
 * h1s stored fp16: 3.2 MB table FITS per-XCD 4 MB L2 -> agg gathers hit L2. */
__global__ __launch_bounds__(256) void k_gemm1(const float* __restrict__ x,
                                               const float* __restrict__ W1,
                                               const int* __restrict__ rinfo,
                                               _Float16* __restrict__ h1s) {
    __shared__ __bf16 wh[16 * 64 * 8];
    __shared__ __bf16 wl[16 * 64 * 8];
    int t = threadIdx.x;
    for (int e = t; e < 8192; e += 256) {
        int c = e >> 9, l = (e >> 3) & 63, j = e & 7;
        int k = c * 32 + ((l >> 4) << 3) + j;
        int n = l & 15;
        float wv = W1[k * HID + n];
        __bf16 h = (__bf16)wv;
        wh[e] = h;
        wl[e] = (__bf16)(wv - (float)h);
    }
    __syncthreads();

    int wave = t >> 6, lane = t & 63;
    int q = lane >> 4, m = lane & 15;
    int row0 = blockIdx.x * 64 + wave * 16;
    int rowa = row0 + m;
    if (rowa >= N_NODES) rowa = N_NODES - 1;
    const float* xr = x + (size_t)rowa * F_IN + q * 8;

    floatx4 acc = {0.f, 0.f, 0.f, 0.f};
    #pragma unroll 4
    for (int c = 0; c < 16; c++) {
        float4 a0 = *(const float4*)(xr + c * 32);
        float4 a1 = *(const float4*)(xr + c * 32 + 4);
        float xv[8] = {a0.x, a0.y, a0.z, a0.w, a1.x, a1.y, a1.z, a1.w};
        bf16x8 ah, al;
        #pragma unroll
        for (int j = 0; j < 8; j++) {
            __bf16 h = (__bf16)xv[j];
            ah[j] = h;
            al[j] = (__bf16)(xv[j] - (float)h);
        }
        bf16x8 bh = *(const bf16x8*)&wh[(c * 64 + lane) * 8];
        bf16x8 bl = *(const bf16x8*)&wl[(c * 64 + lane) * 8];
        acc = __builtin_amdgcn_mfma_f32_16x16x32_bf16(ah, bh, acc, 0, 0, 0);
        acc = __builtin_amdgcn_mfma_f32_16x16x32_bf16(ah, bl, acc, 0, 0, 0);
        acc = __builtin_amdgcn_mfma_f32_16x16x32_bf16(al, bh, acc, 0, 0, 0);
    }
    #pragma unroll
    for (int r = 0; r < 4; r++) {
        int grow = row0 + q * 4 + r;
        if (grow < N_NODES) {
            float dv = rsqrtf((float)(((rinfo[grow] >> 22) & 0x3FF) + 1));
            h1s[grow * HID + (lane & 15)] = (_Float16)(dv * acc[r]);
        }
    }
}

/* ---------------- layer-1 aggregate, node-parallel CSR walk, fp16 table ----------------
 * thread g=(v,k): 16 lanes share v; gather h1s16[c*16+k] -> 32B contiguous per
 * edge per group (L2-hit: 3.2 MB table fits per-XCD L2). Unroll 8 for MLP.
 * Accumulate fp32; fused bias+relu+dinv; store ys fp16. */
__global__ __launch_bounds__(256) void k_agg1(const _Float16* __restrict__ h1s,
        const int* __restrict__ rinfo, const int* __restrict__ col,
        const float* __restrict__ b1, _Float16* __restrict__ ys) {
    int g = blockIdx.x * 256 + threadIdx.x;   /* grid == N*16 exactly */
    int v = g >> 4, k = g & 15;
    int ri = rinfo[v];
    int beg = ri & 0x3FFFFF;
    int deg = (ri >> 22) & 0x3FF;
    int end = beg + deg;
    float s0 = 0.f, s1 = 0.f, s2 = 0.f, s3 = 0.f;
    int j = beg;
    for (; j + 7 < end; j += 8) {
        int c0 = col[j],     c1 = col[j + 1], c2 = col[j + 2], c3 = col[j + 3];
        int c4 = col[j + 4], c5 = col[j + 5], c6 = col[j + 6], c7 = col[j + 7];
        s0 += (float)h1s[c0 * HID + k];
        s1 += (float)h1s[c1 * HID + k];
        s2 += (float)h1s[c2 * HID + k];
        s3 += (float)h1s[c3 * HID + k];
        s0 += (float)h1s[c4 * HID + k];
        s1 += (float)h1s[c5 * HID + k];
        s2 += (float)h1s[c6 * HID + k];
        s3 += (float)h1s[c7 * HID + k];
    }
    for (; j < end; j++) s0 += (float)h1s[col[j] * HID + k];
    float sum = (s0 + s1) + (s2 + s3) + (float)h1s[v * HID + k];  /* self loop */
    float dv = rsqrtf((float)(deg + 1));
    float val = fmaxf(dv * sum + b1[k], 0.f);
    ys[v * HID + k] = (_Float16)(dv * val);   /* pre-scale for layer 2 */
}

/* ---------------- layer-2 aggregate + W2 (16->40) + bias + log_softmax ---------------- */
__global__ __launch_bounds__(256) void k_agg2(const _Float16* __restrict__ ys,
        const int* __restrict__ rinfo, const int* __restrict__ col,
        const float* __restrict__ W2, const float* __restrict__ b2,
        float* __restrict__ out) {
    __shared__ float w2s[HID * NCLS];
    __shared__ float b2s[NCLS];
    int t = threadIdx.x;
    for (int i = t; i < HID * NCLS; i += 256) w2s[i] = W2[i];
    if (t < NCLS) b2s[t] = b2[t];
    __syncthreads();

    int g = blockIdx.x * 256 + t;             /* grid == N*16 exactly */
    int v = g >> 4, l = g & 15;
    int ri = rinfo[v];
    int beg = ri & 0x3FFFFF;
    int deg = (ri >> 22) & 0x3FF;
    int end = beg + deg;
    float s0 = 0.f, s1 = 0.f, s2 = 0.f, s3 = 0.f;
    int j = beg;
    for (; j + 7 < end; j += 8) {
        int c0 = col[j],     c1 = col[j + 1], c2 = col[j + 2], c3 = col[j + 3];
        int c4 = col[j + 4], c5 = col[j + 5], c6 = col[j + 6], c7 = col[j + 7];
        s0 += (float)ys[c0 * HID + l];
        s1 += (float)ys[c1 * HID + l];
        s2 += (float)ys[c2 * HID + l];
        s3 += (float)ys[c3 * HID + l];
        s0 += (float)ys[c4 * HID + l];
        s1 += (float)ys[c5 * HID + l];
        s2 += (float)ys[c6 * HID + l];
        s3 += (float)ys[c7 * HID + l];
    }
    for (; j < end; j++) s0 += (float)ys[col[j] * HID + l];
    float dv = rsqrtf((float)(deg + 1));
    float tval = dv * ((s0 + s1) + (s2 + s3) + (float)ys[v * HID + l]);

    /* 16->40 matvec: lane l covers classes {l, l+16, l+32(l<8)} */
    float acc0 = 0.f, acc1 = 0.f, acc2 = 0.f;
    #pragma unroll
    for (int k = 0; k < 16; k++) {
        float tk = __shfl(tval, k, 16);
        acc0 = fmaf(tk, w2s[k * NCLS + l], acc0);
        acc1 = fmaf(tk, w2s[k * NCLS + l + 16], acc1);
        if (l < 8) acc2 = fmaf(tk, w2s[k * NCLS + l + 32], acc2);
    }
    acc0 += b2s[l];
    acc1 += b2s[l + 16];
    float acc2b = (l < 8) ? (acc2 + b2s[l + 32]) : -1e30f;

    float mx = fmaxf(fmaxf(acc0, acc1), acc2b);
    for (int off = 8; off; off >>= 1) mx = fmaxf(mx, __shfl_xor(mx, off, 16));
    float s = __expf(acc0 - mx) + __expf(acc1 - mx) + __expf(acc2b - mx);
    for (int off = 8; off; off >>= 1) s += __shfl_xor(s, off, 16);
    float lse = mx + __logf(s);

    out[v * NCLS + l] = acc0 - lse;
    out[v * NCLS + l + 16] = acc1 - lse;
    if (l < 8) out[v * NCLS + l + 32] = acc2b - lse;
}

extern "C" void kernel_launch(void* const* d_in, const int* in_sizes, int n_in,
                              void* d_out, int out_size, void* d_ws, size_t ws_size,
                              hipStream_t stream) {
    const float* x  = (const float*)d_in[0];
    const int*   ei = (const int*)d_in[1];
    const float* W1 = (const float*)d_in[2];
    const float* b1 = (const float*)d_in[3];
    const float* W2 = (const float*)d_in[4];
    const float* b2 = (const float*)d_in[5];
    float* out = (float*)d_out;
    const int* src = ei;
    const int* dst = ei + NEDGE;

    char* w = (char*)d_ws;
    size_t o = 0;
    auto alloc = [&](size_t bytes) -> char* {
        char* p = w + o;
        o += (bytes + 511) & ~(size_t)511;
        return p;
    };
    int*      gcnt  = (int*)alloc((size_t)NBUCK * 4);
    int*      rinfo = (int*)alloc((size_t)N_NODES * 4);
    int*      col   = (int*)alloc((size_t)NEDGE * 4);       /* 12.8 MB dense CSR */
    /* union: ebuf (13.8 MB, dead after k_sortb) overlaps h1s+ys (fp16, 6.4 MB
     * total, first written by k_gemm1 which runs after k_sortb — stream order) */
    char*     uni   = alloc((size_t)NBUCK * BCAP * 4);
    int*      ebuf  = (int*)uni;
    _Float16* h1s   = (_Float16*)uni;
    _Float16* ys    = h1s + (size_t)N_NODES * HID;
    /* total ~27.02 MB <= proven 27.03 MB */

    hipMemsetAsync(gcnt, 0, (size_t)NBUCK * 4, stream);

    k_part <<<NPART, 256, 0, stream>>>(src, dst, gcnt, ebuf);
    k_sortb<<<NBUCK, 256, 0, stream>>>(gcnt, ebuf, col, rinfo);
    k_gemm1<<<(N_NODES + 63) / 64, 256, 0, stream>>>(x, W1, rinfo, h1s);
    k_agg1 <<<(N_NODES * HID) / 256, 256, 0, stream>>>(h1s, rinfo, col, b1, ys);
    k_agg2 <<<(N_NODES * HID) / 256, 256, 0, stream>>>(ys, rinfo, col, W2, b2, out);
}

// Round 8
// 449.019 us; speedup vs baseline: 2.3579x; 1.0146x over previous
//
#include <hip/hip_runtime.h>

#define N_NODES 100000
#define NEDGE   3200000
#define F_IN    512
#define HID     16
#define NCLS    40

/* ---- dst-bucket partition geometry ---- */
#define BSHIFT  8
#define BNODES  256                                  /* nodes per bucket */
#define NBUCK   ((N_NODES + BNODES - 1) / BNODES)    /* 391 */
#define BCAP    8832    /* mean 8192, sd ~90 -> +7 sigma */
#define EPB     5120    /* edges per partition block: 256 thr x 4 x 5 */
#define NPART   (NEDGE / EPB)                        /* 625, exact */

typedef __bf16 bf16x8 __attribute__((ext_vector_type(8)));
typedef float floatx4 __attribute__((ext_vector_type(4)));
typedef _Float16 f16x4 __attribute__((ext_vector_type(4)));

/* ---------------- edge partition by dst bucket (proven r6/r7) ---------------- */
__global__ __launch_bounds__(256) void k_part(const int* __restrict__ src,
                                              const int* __restrict__ dst,
                                              int* __restrict__ gcnt,
                                              int* __restrict__ ebuf) {
    __shared__ int hist[NBUCK];
    int t = threadIdx.x;
    for (int i = t; i < NBUCK; i += 256) hist[i] = 0;
    __syncthreads();

    int base = blockIdx.x * EPB + t * 4;
    int4 dr[5];
    #pragma unroll
    for (int s = 0; s < 5; s++) {
        dr[s] = *(const int4*)(dst + base + s * 1024);
        atomicAdd(&hist[dr[s].x >> BSHIFT], 1);
        atomicAdd(&hist[dr[s].y >> BSHIFT], 1);
        atomicAdd(&hist[dr[s].z >> BSHIFT], 1);
        atomicAdd(&hist[dr[s].w >> BSHIFT], 1);
    }
    __syncthreads();

    for (int i = t; i < NBUCK; i += 256) {
        int h = hist[i];
        hist[i] = h ? atomicAdd(&gcnt[i], h) : 0;
    }
    __syncthreads();

    #pragma unroll
    for (int s = 0; s < 5; s++) {
        int4 s4 = *(const int4*)(src + base + s * 1024);
        int dd[4] = {dr[s].x, dr[s].y, dr[s].z, dr[s].w};
        int ss[4] = {s4.x, s4.y, s4.z, s4.w};
        #pragma unroll
        for (int j = 0; j < 4; j++) {
            int d = dd[j];
            int b = d >> BSHIFT;
            int p = atomicAdd(&hist[b], 1);
            if (p < BCAP) ebuf[b * BCAP + p] = ((d & (BNODES - 1)) << 17) | ss[j];
        }
    }
}

/* ---------------- per-bucket counting sort -> dense CSR (proven r6/r7) ---------------- */
__global__ __launch_bounds__(256) void k_sortb(const int* __restrict__ gcnt,
                                               const int* __restrict__ ebuf,
                                               int* __restrict__ col,
                                               int* __restrict__ rinfo) {
    __shared__ int ed[BCAP];
    __shared__ int cnt[BNODES];
    __shared__ int pref[BNODES];
    int b = blockIdx.x, t = threadIdx.x;

    int partial = 0;
    for (int i = t; i < b; i += 256) partial += gcnt[i];
    pref[t] = partial;
    __syncthreads();
    for (int off = 128; off; off >>= 1) {
        if (t < off) pref[t] += pref[t + off];
        __syncthreads();
    }
    int gbase = pref[0];
    __syncthreads();

    int ne = gcnt[b];
    if (ne > BCAP) ne = BCAP;
    cnt[t] = 0;
    __syncthreads();
    for (int i = t; i < ne; i += 256) {
        int e = ebuf[b * BCAP + i];
        ed[i] = e;
        atomicAdd(&cnt[e >> 17], 1);
    }
    __syncthreads();
    int c = cnt[t];
    pref[t] = c;
    __syncthreads();
    for (int off = 1; off < 256; off <<= 1) {
        int add = (t >= off) ? pref[t - off] : 0;
        __syncthreads();
        pref[t] += add;
        __syncthreads();
    }
    int start = pref[t] - c;
    int v = b * BNODES + t;
    if (v < N_NODES) rinfo[v] = (c << 22) | (gbase + start);
    cnt[t] = start;
    __syncthreads();
    for (int i = t; i < ne; i += 256) {
        int e = ed[i];
        int pos = atomicAdd(&cnt[e >> 17], 1);
        col[gbase + pos] = e & 0x1FFFF;
    }
}

/* ---------------- GEMM1: h1s(fp16) = dinv * (x @ W1) (proven r7) ---------------- */
__global__ __launch_bounds__(256) void k_gemm1(const float* __restrict__ x,
                                               const float* __restrict__ W1,
                                               const int* __restrict__ rinfo,
                                               _Float16* __restrict__ h1s) {
    __shared__ __bf16 wh[16 * 64 * 8];
    __shared__ __bf16 wl[16 * 64 * 8];
    int t = threadIdx.x;
    for (int e = t; e < 8192; e += 256) {
        int c = e >> 9, l = (e >> 3) & 63, j = e & 7;
        int k = c * 32 + ((l >> 4) << 3) + j;
        int n = l & 15;
        float wv = W1[k * HID + n];
        __bf16 h = (__bf16)wv;
        wh[e] = h;
        wl[e] = (__bf16)(wv - (float)h);
    }
    __syncthreads();

    int wave = t >> 6, lane = t & 63;
    int q = lane >> 4, m = lane & 15;
    int row0 = blockIdx.x * 64 + wave * 16;
    int rowa = row0 + m;
    if (rowa >= N_NODES) rowa = N_NODES - 1;
    const float* xr = x + (size_t)rowa * F_IN + q * 8;

    floatx4 acc = {0.f, 0.f, 0.f, 0.f};
    #pragma unroll 4
    for (int c = 0; c < 16; c++) {
        float4 a0 = *(const float4*)(xr + c * 32);
        float4 a1 = *(const float4*)(xr + c * 32 + 4);
        float xv[8] = {a0.x, a0.y, a0.z, a0.w, a1.x, a1.y, a1.z, a1.w};
        bf16x8 ah, al;
        #pragma unroll
        for (int j = 0; j < 8; j++) {
            __bf16 h = (__bf16)xv[j];
            ah[j] = h;
            al[j] = (__bf16)(xv[j] - (float)h);
        }
        bf16x8 bh = *(const bf16x8*)&wh[(c * 64 + lane) * 8];
        bf16x8 bl = *(const bf16x8*)&wl[(c * 64 + lane) * 8];
        acc = __builtin_amdgcn_mfma_f32_16x16x32_bf16(ah, bh, acc, 0, 0, 0);
        acc = __builtin_amdgcn_mfma_f32_16x16x32_bf16(ah, bl, acc, 0, 0, 0);
        acc = __builtin_amdgcn_mfma_f32_16x16x32_bf16(al, bh, acc, 0, 0, 0);
    }
    #pragma unroll
    for (int r = 0; r < 4; r++) {
        int grow = row0 + q * 4 + r;
        if (grow < N_NODES) {
            float dv = rsqrtf((float)(((rinfo[grow] >> 22) & 0x3FF) + 1));
            h1s[grow * HID + (lane & 15)] = (_Float16)(dv * acc[r]);
        }
    }
}

#define ACC4(gv) { a0 += (float)gv[0]; a1 += (float)gv[1]; \
                   a2 += (float)gv[2]; a3 += (float)gv[3]; }

/* ---------------- layer-1 aggregate: 4 lanes/node, f16x4 gathers ----------------
 * thread (v,q) owns k=4q..4q+3: one col index feeds 4 k-slots, gather is
 * dwordx2 (4 lanes -> one 32B line/edge). Unroll 8, 4 indep acc chains. */
__global__ __launch_bounds__(256) void k_agg1(const _Float16* __restrict__ h1s,
        const int* __restrict__ rinfo, const int* __restrict__ col,
        const float* __restrict__ b1, _Float16* __restrict__ ys) {
    int g = blockIdx.x * 256 + threadIdx.x;
    int v = g >> 2, q = g & 3;
    if (v >= N_NODES) return;
    int ri = rinfo[v];
    int beg = ri & 0x3FFFFF;
    int deg = (ri >> 22) & 0x3FF;
    int end = beg + deg;
    const f16x4* tab = (const f16x4*)h1s;
    float a0 = 0.f, a1 = 0.f, a2 = 0.f, a3 = 0.f;
    int j = beg;
    for (; j + 7 < end; j += 8) {
        int c0 = col[j],     c1 = col[j + 1], c2 = col[j + 2], c3 = col[j + 3];
        int c4 = col[j + 4], c5 = col[j + 5], c6 = col[j + 6], c7 = col[j + 7];
        f16x4 g0 = tab[c0 * 4 + q], g1 = tab[c1 * 4 + q];
        f16x4 g2 = tab[c2 * 4 + q], g3 = tab[c3 * 4 + q];
        f16x4 g4 = tab[c4 * 4 + q], g5 = tab[c5 * 4 + q];
        f16x4 g6 = tab[c6 * 4 + q], g7 = tab[c7 * 4 + q];
        ACC4(g0) ACC4(g1) ACC4(g2) ACC4(g3)
        ACC4(g4) ACC4(g5) ACC4(g6) ACC4(g7)
    }
    for (; j < end; j++) {
        f16x4 gv = tab[col[j] * 4 + q];
        ACC4(gv)
    }
    f16x4 sv = tab[v * 4 + q];          /* self loop (h1s already dinv-scaled) */
    ACC4(sv)
    float dv = rsqrtf((float)(deg + 1));
    f16x4 o;
    o[0] = (_Float16)(dv * fmaxf(dv * a0 + b1[q * 4 + 0], 0.f));
    o[1] = (_Float16)(dv * fmaxf(dv * a1 + b1[q * 4 + 1], 0.f));
    o[2] = (_Float16)(dv * fmaxf(dv * a2 + b1[q * 4 + 2], 0.f));
    o[3] = (_Float16)(dv * fmaxf(dv * a3 + b1[q * 4 + 3], 0.f));
    ((f16x4*)ys)[v * 4 + q] = o;        /* pre-scaled for layer 2 */
}

/* ---------------- layer-2 aggregate + W2 (16->40) + bias + log_softmax ----------------
 * Same 4-lane gather core; lane q holds tv[k=4q..4q+3]; width-4 shuffles
 * broadcast tv for the matvec; lane q emits classes [10q, 10q+10). */
__global__ __launch_bounds__(256) void k_agg2(const _Float16* __restrict__ ys,
        const int* __restrict__ rinfo, const int* __restrict__ col,
        const float* __restrict__ W2, const float* __restrict__ b2,
        float* __restrict__ out) {
    __shared__ float w2s[HID * NCLS];
    __shared__ float b2s[NCLS];
    int t = threadIdx.x;
    for (int i = t; i < HID * NCLS; i += 256) w2s[i] = W2[i];
    if (t < NCLS) b2s[t] = b2[t];
    __syncthreads();

    int g = blockIdx.x * 256 + t;
    int v = g >> 2, q = g & 3;
    if (v >= N_NODES) return;
    int ri = rinfo[v];
    int beg = ri & 0x3FFFFF;
    int deg = (ri >> 22) & 0x3FF;
    int end = beg + deg;
    const f16x4* tab = (const f16x4*)ys;
    float a0 = 0.f, a1 = 0.f, a2 = 0.f, a3 = 0.f;
    int j = beg;
    for (; j + 7 < end; j += 8) {
        int c0 = col[j],     c1 = col[j + 1], c2 = col[j + 2], c3 = col[j + 3];
        int c4 = col[j + 4], c5 = col[j + 5], c6 = col[j + 6], c7 = col[j + 7];
        f16x4 g0 = tab[c0 * 4 + q], g1 = tab[c1 * 4 + q];
        f16x4 g2 = tab[c2 * 4 + q], g3 = tab[c3 * 4 + q];
        f16x4 g4 = tab[c4 * 4 + q], g5 = tab[c5 * 4 + q];
        f16x4 g6 = tab[c6 * 4 + q], g7 = tab[c7 * 4 + q];
        ACC4(g0) ACC4(g1) ACC4(g2) ACC4(g3)
        ACC4(g4) ACC4(g5) ACC4(g6) ACC4(g7)
    }
    for (; j < end; j++) {
        f16x4 gv = tab[col[j] * 4 + q];
        ACC4(gv)
    }
    f16x4 sv = tab[v * 4 + q];          /* self loop */
    ACC4(sv)
    float dv = rsqrtf((float)(deg + 1));
    float tv[4] = {dv * a0, dv * a1, dv * a2, dv * a3};

    float lg[10];
    #pragma unroll
    for (int i = 0; i < 10; i++) lg[i] = b2s[q * 10 + i];
    #pragma unroll
    for (int k = 0; k < 16; k++) {
        float tk = __shfl(tv[k & 3], k >> 2, 4);
        #pragma unroll
        for (int i = 0; i < 10; i++)
            lg[i] = fmaf(tk, w2s[k * NCLS + q * 10 + i], lg[i]);
    }
    float mx = lg[0];
    #pragma unroll
    for (int i = 1; i < 10; i++) mx = fmaxf(mx, lg[i]);
    mx = fmaxf(mx, __shfl_xor(mx, 1, 4));
    mx = fmaxf(mx, __shfl_xor(mx, 2, 4));
    float s = 0.f;
    #pragma unroll
    for (int i = 0; i < 10; i++) s += __expf(lg[i] - mx);
    s += __shfl_xor(s, 1, 4);
    s += __shfl_xor(s, 2, 4);
    float lse = mx + __logf(s);
    #pragma unroll
    for (int i = 0; i < 10; i++) out[v * NCLS + q * 10 + i] = lg[i] - lse;
}

extern "C" void kernel_launch(void* const* d_in, const int* in_sizes, int n_in,
                              void* d_out, int out_size, void* d_ws, size_t ws_size,
                              hipStream_t stream) {
    const float* x  = (const float*)d_in[0];
    const int*   ei = (const int*)d_in[1];
    const float* W1 = (const float*)d_in[2];
    const float* b1 = (const float*)d_in[3];
    const float* W2 = (const float*)d_in[4];
    const float* b2 = (const float*)d_in[5];
    float* out = (float*)d_out;
    const int* src = ei;
    const int* dst = ei + NEDGE;

    char* w = (char*)d_ws;
    size_t o = 0;
    auto alloc = [&](size_t bytes) -> char* {
        char* p = w + o;
        o += (bytes + 511) & ~(size_t)511;
        return p;
    };
    int*      gcnt  = (int*)alloc((size_t)NBUCK * 4);
    int*      rinfo = (int*)alloc((size_t)N_NODES * 4);
    int*      col   = (int*)alloc((size_t)NEDGE * 4);       /* 12.8 MB dense CSR */
    /* union: ebuf (13.8 MB, dead after k_sortb) overlaps h1s+ys (fp16, 6.4 MB) */
    char*     uni   = alloc((size_t)NBUCK * BCAP * 4);
    int*      ebuf  = (int*)uni;
    _Float16* h1s   = (_Float16*)uni;
    _Float16* ys    = h1s + (size_t)N_NODES * HID;
    /* total ~27.02 MB <= proven 27.03 MB */

    hipMemsetAsync(gcnt, 0, (size_t)NBUCK * 4, stream);

    k_part <<<NPART, 256, 0, stream>>>(src, dst, gcnt, ebuf);
    k_sortb<<<NBUCK, 256, 0, stream>>>(gcnt, ebuf, col, rinfo);
    k_gemm1<<<(N_NODES + 63) / 64, 256, 0, stream>>>(x, W1, rinfo, h1s);
    k_agg1 <<<(N_NODES * 4 + 255) / 256, 256, 0, stream>>>(h1s, rinfo, col, b1, ys);
    k_agg2 <<<(N_NODES * 4 + 255) / 256, 256, 0, stream>>>(ys, rinfo, col, W2, b2, out);
}

// Round 9
// 431.344 us; speedup vs baseline: 2.4545x; 1.0410x over previous
//
#include <hip/hip_runtime.h>

#define N_NODES 100000
#define NEDGE   3200000
#define F_IN    512
#define HID     16
#define NCLS    40

/* ---- dst-bucket partition geometry ---- */
#define BSHIFT  8
#define BNODES  256                                  /* nodes per bucket */
#define NBUCK   ((N_NODES + BNODES - 1) / BNODES)    /* 391 */
#define BCAP    8832    /* mean 8192, sd ~90 -> +7 sigma */
#define EPB     5120    /* edges per partition block: 256 thr x 4 x 5 */
#define NPART   (NEDGE / EPB)                        /* 625, exact */
#define NGEMM   ((N_NODES + 63) / 64)                /* 1563 */

typedef __bf16 bf16x8 __attribute__((ext_vector_type(8)));
typedef float floatx4 __attribute__((ext_vector_type(4)));
typedef _Float16 f16x4 __attribute__((ext_vector_type(4)));

/* ---------------- fused: edge partition (blocks 0..NPART) ----------------
 *                + GEMM1 h1u = x @ W1, unscaled (blocks NPART..NPART+NGEMM)
 * The two roles are data-independent: partition is latency/atomic-bound,
 * GEMM is MFMA/BW-bound -> co-resident blocks overlap the two phases that
 * previously serialized on the stream. LDS: 32 KB union (gemm needs all,
 * part uses first 1.6 KB). */
__global__ __launch_bounds__(256) void k_partgemm(
        const int* __restrict__ src, const int* __restrict__ dst,
        int* __restrict__ gcnt, int* __restrict__ ebuf,
        const float* __restrict__ x, const float* __restrict__ W1,
        _Float16* __restrict__ h1u) {
    __shared__ char smraw[32768];
    int t = threadIdx.x;

    if (blockIdx.x < NPART) {
        /* ----- partition role (proven r6/r7/r8 k_part, hist -> smraw) ----- */
        int* hist = (int*)smraw;
        for (int i = t; i < NBUCK; i += 256) hist[i] = 0;
        __syncthreads();

        int base = blockIdx.x * EPB + t * 4;
        int4 dr[5];
        #pragma unroll
        for (int s = 0; s < 5; s++) {
            dr[s] = *(const int4*)(dst + base + s * 1024);
            atomicAdd(&hist[dr[s].x >> BSHIFT], 1);
            atomicAdd(&hist[dr[s].y >> BSHIFT], 1);
            atomicAdd(&hist[dr[s].z >> BSHIFT], 1);
            atomicAdd(&hist[dr[s].w >> BSHIFT], 1);
        }
        __syncthreads();

        for (int i = t; i < NBUCK; i += 256) {
            int h = hist[i];
            hist[i] = h ? atomicAdd(&gcnt[i], h) : 0;
        }
        __syncthreads();

        #pragma unroll
        for (int s = 0; s < 5; s++) {
            int4 s4 = *(const int4*)(src + base + s * 1024);
            int dd[4] = {dr[s].x, dr[s].y, dr[s].z, dr[s].w};
            int ss[4] = {s4.x, s4.y, s4.z, s4.w};
            #pragma unroll
            for (int j = 0; j < 4; j++) {
                int d = dd[j];
                int b = d >> BSHIFT;
                int p = atomicAdd(&hist[b], 1);
                if (p < BCAP) ebuf[b * BCAP + p] = ((d & (BNODES - 1)) << 17) | ss[j];
            }
        }
    } else {
        /* ----- GEMM role (r7/r8 k_gemm1 minus the dinv scale/rinfo dep) ----- */
        __bf16* wh = (__bf16*)smraw;
        __bf16* wl = wh + 8192;
        for (int e = t; e < 8192; e += 256) {
            int c = e >> 9, l = (e >> 3) & 63, j = e & 7;
            int k = c * 32 + ((l >> 4) << 3) + j;
            int n = l & 15;
            float wv = W1[k * HID + n];
            __bf16 h = (__bf16)wv;
            wh[e] = h;
            wl[e] = (__bf16)(wv - (float)h);
        }
        __syncthreads();

        int wave = t >> 6, lane = t & 63;
        int q = lane >> 4, m = lane & 15;
        int row0 = (blockIdx.x - NPART) * 64 + wave * 16;
        int rowa = row0 + m;
        if (rowa >= N_NODES) rowa = N_NODES - 1;
        const float* xr = x + (size_t)rowa * F_IN + q * 8;

        floatx4 acc = {0.f, 0.f, 0.f, 0.f};
        #pragma unroll 4
        for (int c = 0; c < 16; c++) {
            float4 a0 = *(const float4*)(xr + c * 32);
            float4 a1 = *(const float4*)(xr + c * 32 + 4);
            float xv[8] = {a0.x, a0.y, a0.z, a0.w, a1.x, a1.y, a1.z, a1.w};
            bf16x8 ah, al;
            #pragma unroll
            for (int j = 0; j < 8; j++) {
                __bf16 h = (__bf16)xv[j];
                ah[j] = h;
                al[j] = (__bf16)(xv[j] - (float)h);
            }
            bf16x8 bh = *(const bf16x8*)&wh[(c * 64 + lane) * 8];
            bf16x8 bl = *(const bf16x8*)&wl[(c * 64 + lane) * 8];
            acc = __builtin_amdgcn_mfma_f32_16x16x32_bf16(ah, bh, acc, 0, 0, 0);
            acc = __builtin_amdgcn_mfma_f32_16x16x32_bf16(ah, bl, acc, 0, 0, 0);
            acc = __builtin_amdgcn_mfma_f32_16x16x32_bf16(al, bh, acc, 0, 0, 0);
        }
        #pragma unroll
        for (int r = 0; r < 4; r++) {
            int grow = row0 + q * 4 + r;
            if (grow < N_NODES)
                h1u[grow * HID + (lane & 15)] = (_Float16)acc[r];
        }
    }
}

/* ---------------- per-bucket counting sort -> dense CSR (proven r6-r8)
 * + epilogue: scale this bucket's h1u rows by dinv (deg is in cnt[]) ---------------- */
__global__ __launch_bounds__(256) void k_sortb(const int* __restrict__ gcnt,
                                               const int* __restrict__ ebuf,
                                               int* __restrict__ col,
                                               int* __restrict__ rinfo,
                                               _Float16* __restrict__ h1) {
    __shared__ int ed[BCAP];
    __shared__ int cnt[BNODES];
    __shared__ int pref[BNODES];
    int b = blockIdx.x, t = threadIdx.x;

    int partial = 0;
    for (int i = t; i < b; i += 256) partial += gcnt[i];
    pref[t] = partial;
    __syncthreads();
    for (int off = 128; off; off >>= 1) {
        if (t < off) pref[t] += pref[t + off];
        __syncthreads();
    }
    int gbase = pref[0];
    __syncthreads();

    int ne = gcnt[b];
    if (ne > BCAP) ne = BCAP;
    cnt[t] = 0;
    __syncthreads();
    for (int i = t; i < ne; i += 256) {
        int e = ebuf[b * BCAP + i];
        ed[i] = e;
        atomicAdd(&cnt[e >> 17], 1);
    }
    __syncthreads();
    int c = cnt[t];
    pref[t] = c;
    __syncthreads();
    for (int off = 1; off < 256; off <<= 1) {
        int add = (t >= off) ? pref[t - off] : 0;
        __syncthreads();
        pref[t] += add;
        __syncthreads();
    }
    int start = pref[t] - c;
    int v = b * BNODES + t;
    if (v < N_NODES) {
        rinfo[v] = (c << 22) | (gbase + start);
        /* scale h1u row -> h1s = dinv * (x@W1) for this node (coalesced 32B) */
        float dv = rsqrtf((float)(c + 1));
        f16x4* row = (f16x4*)(h1 + (size_t)v * HID);
        #pragma unroll
        for (int r = 0; r < 4; r++) {
            f16x4 vv = row[r];
            vv[0] = (_Float16)(dv * (float)vv[0]);
            vv[1] = (_Float16)(dv * (float)vv[1]);
            vv[2] = (_Float16)(dv * (float)vv[2]);
            vv[3] = (_Float16)(dv * (float)vv[3]);
            row[r] = vv;
        }
    }
    cnt[t] = start;
    __syncthreads();
    for (int i = t; i < ne; i += 256) {
        int e = ed[i];
        int pos = atomicAdd(&cnt[e >> 17], 1);
        col[gbase + pos] = e & 0x1FFFF;
    }
}

#define ACC4(gv) { a0 += (float)gv[0]; a1 += (float)gv[1]; \
                   a2 += (float)gv[2]; a3 += (float)gv[3]; }

/* ---------------- layer-1 aggregate: 4 lanes/node, f16x4 gathers (proven r8) ---------------- */
__global__ __launch_bounds__(256) void k_agg1(const _Float16* __restrict__ h1s,
        const int* __restrict__ rinfo, const int* __restrict__ col,
        const float* __restrict__ b1, _Float16* __restrict__ ys) {
    int g = blockIdx.x * 256 + threadIdx.x;
    int v = g >> 2, q = g & 3;
    if (v >= N_NODES) return;
    int ri = rinfo[v];
    int beg = ri & 0x3FFFFF;
    int deg = (ri >> 22) & 0x3FF;
    int end = beg + deg;
    const f16x4* tab = (const f16x4*)h1s;
    float a0 = 0.f, a1 = 0.f, a2 = 0.f, a3 = 0.f;
    int j = beg;
    for (; j + 7 < end; j += 8) {
        int c0 = col[j],     c1 = col[j + 1], c2 = col[j + 2], c3 = col[j + 3];
        int c4 = col[j + 4], c5 = col[j + 5], c6 = col[j + 6], c7 = col[j + 7];
        f16x4 g0 = tab[c0 * 4 + q], g1 = tab[c1 * 4 + q];
        f16x4 g2 = tab[c2 * 4 + q], g3 = tab[c3 * 4 + q];
        f16x4 g4 = tab[c4 * 4 + q], g5 = tab[c5 * 4 + q];
        f16x4 g6 = tab[c6 * 4 + q], g7 = tab[c7 * 4 + q];
        ACC4(g0) ACC4(g1) ACC4(g2) ACC4(g3)
        ACC4(g4) ACC4(g5) ACC4(g6) ACC4(g7)
    }
    for (; j < end; j++) {
        f16x4 gv = tab[col[j] * 4 + q];
        ACC4(gv)
    }
    f16x4 sv = tab[v * 4 + q];          /* self loop (h1s dinv-scaled in k_sortb) */
    ACC4(sv)
    float dv = rsqrtf((float)(deg + 1));
    f16x4 o;
    o[0] = (_Float16)(dv * fmaxf(dv * a0 + b1[q * 4 + 0], 0.f));
    o[1] = (_Float16)(dv * fmaxf(dv * a1 + b1[q * 4 + 1], 0.f));
    o[2] = (_Float16)(dv * fmaxf(dv * a2 + b1[q * 4 + 2], 0.f));
    o[3] = (_Float16)(dv * fmaxf(dv * a3 + b1[q * 4 + 3], 0.f));
    ((f16x4*)ys)[v * 4 + q] = o;        /* pre-scaled for layer 2 */
}

/* ---------------- layer-2 aggregate + W2 + bias + log_softmax (proven r8) ---------------- */
__global__ __launch_bounds__(256) void k_agg2(const _Float16* __restrict__ ys,
        const int* __restrict__ rinfo, const int* __restrict__ col,
        const float* __restrict__ W2, const float* __restrict__ b2,
        float* __restrict__ out) {
    __shared__ float w2s[HID * NCLS];
    __shared__ float b2s[NCLS];
    int t = threadIdx.x;
    for (int i = t; i < HID * NCLS; i += 256) w2s[i] = W2[i];
    if (t < NCLS) b2s[t] = b2[t];
    __syncthreads();

    int g = blockIdx.x * 256 + t;
    int v = g >> 2, q = g & 3;
    if (v >= N_NODES) return;
    int ri = rinfo[v];
    int beg = ri & 0x3FFFFF;
    int deg = (ri >> 22) & 0x3FF;
    int end = beg + deg;
    const f16x4* tab = (const f16x4*)ys;
    float a0 = 0.f, a1 = 0.f, a2 = 0.f, a3 = 0.f;
    int j = beg;
    for (; j + 7 < end; j += 8) {
        int c0 = col[j],     c1 = col[j + 1], c2 = col[j + 2], c3 = col[j + 3];
        int c4 = col[j + 4], c5 = col[j + 5], c6 = col[j + 6], c7 = col[j + 7];
        f16x4 g0 = tab[c0 * 4 + q], g1 = tab[c1 * 4 + q];
        f16x4 g2 = tab[c2 * 4 + q], g3 = tab[c3 * 4 + q];
        f16x4 g4 = tab[c4 * 4 + q], g5 = tab[c5 * 4 + q];
        f16x4 g6 = tab[c6 * 4 + q], g7 = tab[c7 * 4 + q];
        ACC4(g0) ACC4(g1) ACC4(g2) ACC4(g3)
        ACC4(g4) ACC4(g5) ACC4(g6) ACC4(g7)
    }
    for (; j < end; j++) {
        f16x4 gv = tab[col[j] * 4 + q];
        ACC4(gv)
    }
    f16x4 sv = tab[v * 4 + q];          /* self loop */
    ACC4(sv)
    float dv = rsqrtf((float)(deg + 1));
    float tv[4] = {dv * a0, dv * a1, dv * a2, dv * a3};

    float lg[10];
    #pragma unroll
    for (int i = 0; i < 10; i++) lg[i] = b2s[q * 10 + i];
    #pragma unroll
    for (int k = 0; k < 16; k++) {
        float tk = __shfl(tv[k & 3], k >> 2, 4);
        #pragma unroll
        for (int i = 0; i < 10; i++)
            lg[i] = fmaf(tk, w2s[k * NCLS + q * 10 + i], lg[i]);
    }
    float mx = lg[0];
    #pragma unroll
    for (int i = 1; i < 10; i++) mx = fmaxf(mx, lg[i]);
    mx = fmaxf(mx, __shfl_xor(mx, 1, 4));
    mx = fmaxf(mx, __shfl_xor(mx, 2, 4));
    float s = 0.f;
    #pragma unroll
    for (int i = 0; i < 10; i++) s += __expf(lg[i] - mx);
    s += __shfl_xor(s, 1, 4);
    s += __shfl_xor(s, 2, 4);
    float lse = mx + __logf(s);
    #pragma unroll
    for (int i = 0; i < 10; i++) out[v * NCLS + q * 10 + i] = lg[i] - lse;
}

extern "C" void kernel_launch(void* const* d_in, const int* in_sizes, int n_in,
                              void* d_out, int out_size, void* d_ws, size_t ws_size,
                              hipStream_t stream) {
    const float* x  = (const float*)d_in[0];
    const int*   ei = (const int*)d_in[1];
    const float* W1 = (const float*)d_in[2];
    const float* b1 = (const float*)d_in[3];
    const float* W2 = (const float*)d_in[4];
    const float* b2 = (const float*)d_in[5];
    float* out = (float*)d_out;
    const int* src = ei;
    const int* dst = ei + NEDGE;

    char* w = (char*)d_ws;
    size_t o = 0;
    auto alloc = [&](size_t bytes) -> char* {
        char* p = w + o;
        o += (bytes + 511) & ~(size_t)511;
        return p;
    };
    int*      gcnt  = (int*)alloc((size_t)NBUCK * 4);
    int*      rinfo = (int*)alloc((size_t)N_NODES * 4);
    int*      col   = (int*)alloc((size_t)NEDGE * 4);       /* 12.8 MB dense CSR */
    int*      ebuf  = (int*)alloc((size_t)NBUCK * BCAP * 4);/* 13.8 MB */
    /* h1s/ys can no longer union with ebuf (gemm writes h1u while part writes
     * ebuf in the same fused kernel) — allocate separately (fp16, 6.4 MB) */
    _Float16* h1s   = (_Float16*)alloc((size_t)N_NODES * HID * 2);
    _Float16* ys    = (_Float16*)alloc((size_t)N_NODES * HID * 2);
    /* total ~33.5 MB (ws_size is ~800 MB per fillBuffer WRITE_SIZE — ample) */

    hipMemsetAsync(gcnt, 0, (size_t)NBUCK * 4, stream);

    k_partgemm<<<NPART + NGEMM, 256, 0, stream>>>(src, dst, gcnt, ebuf, x, W1, h1s);
    k_sortb   <<<NBUCK, 256, 0, stream>>>(gcnt, ebuf, col, rinfo, h1s);
    k_agg1    <<<(N_NODES * 4 + 255) / 256, 256, 0, stream>>>(h1s, rinfo, col, b1, ys);
    k_agg2    <<<(N_NODES * 4 + 255) / 256, 256, 0, stream>>>(ys, rinfo, col, W2, b2, out);
}

// Round 10
// 423.973 us; speedup vs baseline: 2.4972x; 1.0174x over previous
//
#include <hip/hip_runtime.h>

#define N_NODES 100000
#define NEDGE   3200000
#define F_IN    512
#define HID     16
#define NCLS    40

/* ---- dst-bucket partition geometry ---- */
#define BSHIFT  8
#define BNODES  256                                  /* nodes per bucket */
#define NBUCK   ((N_NODES + BNODES - 1) / BNODES)    /* 391 */
#define BCAP    8832    /* mean 8192, sd ~90 -> +7 sigma */
#define EPB     5120    /* edges per partition block: 256 thr x 4 x 5 */
#define NPART   (NEDGE / EPB)                        /* 625, exact */
#define NGEMM   ((N_NODES + 63) / 64)                /* 1563 */

typedef __bf16 bf16x8 __attribute__((ext_vector_type(8)));
typedef float floatx4 __attribute__((ext_vector_type(4)));
typedef _Float16 f16x4 __attribute__((ext_vector_type(4)));

/* ---------------- fused: edge partition (blocks 0..NPART) ----------------
 *                + GEMM1 h1u = x @ W1, unscaled (blocks NPART..)
 * Partition role now does a block-local counting sort in LDS and flushes
 * bucket-sorted runs -> coalesced ~52B write transactions instead of 3.2M
 * scattered 4B writes (r9 PMC: WRITE 72MB vs 17 ideal, all pipes idle).
 * LDS 36KB (gemm uses 32KB) -> still 4 blocks/CU. */
__global__ __launch_bounds__(256) void k_partgemm(
        const int* __restrict__ src, const int* __restrict__ dst,
        int* __restrict__ gcnt, int* __restrict__ ebuf,
        const float* __restrict__ x, const float* __restrict__ W1,
        _Float16* __restrict__ h1u) {
    __shared__ char smraw[36864];
    int t = threadIdx.x;

    if (blockIdx.x < NPART) {
        /* ----- partition role with LDS sort ----- */
        int* hist  = (int*)smraw;                         /* 512 ints: counts -> global base */
        int* lpref = hist + 512;                          /* 512 ints: local excl prefix */
        int* cur   = lpref + 512;                         /* 512 ints: scanbuf, then cursors */
        int* ed    = cur + 512;                           /* 5120 ints: sorted entries */
        unsigned short* abuf = (unsigned short*)(ed + EPB);  /* 5120: bucket id per slot */

        for (int i = t; i < NBUCK; i += 256) hist[i] = 0;
        __syncthreads();

        int base = blockIdx.x * EPB + t * 4;
        int4 dr[5];
        #pragma unroll
        for (int s = 0; s < 5; s++) {
            dr[s] = *(const int4*)(dst + base + s * 1024);
            atomicAdd(&hist[dr[s].x >> BSHIFT], 1);
            atomicAdd(&hist[dr[s].y >> BSHIFT], 1);
            atomicAdd(&hist[dr[s].z >> BSHIFT], 1);
            atomicAdd(&hist[dr[s].w >> BSHIFT], 1);
        }
        __syncthreads();

        /* local exclusive prefix over NBUCK counts: 2 blocked bins/thread */
        int c0 = 0, c1 = 0;
        if (t < 196) {
            c0 = hist[2 * t];
            c1 = (2 * t + 1 < NBUCK) ? hist[2 * t + 1] : 0;
        }
        int sums = c0 + c1;
        cur[t] = sums;                    /* cur as scanbuf */
        __syncthreads();
        for (int off = 1; off < 256; off <<= 1) {
            int add = (t >= off) ? cur[t - off] : 0;
            __syncthreads();
            cur[t] += add;
            __syncthreads();
        }
        if (t < 196) {
            int excl = cur[t] - sums;
            lpref[2 * t] = excl;
            if (2 * t + 1 < NBUCK) lpref[2 * t + 1] = excl + c0;
        }
        __syncthreads();

        /* reserve global runs (hist becomes per-bucket global base offset) */
        for (int i = t; i < NBUCK; i += 256) {
            int c = hist[i];
            hist[i] = c ? atomicAdd(&gcnt[i], c) : 0;
        }
        for (int i = t; i < 512; i += 256) cur[i] = 0;   /* re-zero cursors */
        __syncthreads();

        /* scatter into bucket-sorted LDS layout */
        #pragma unroll
        for (int s = 0; s < 5; s++) {
            int4 s4 = *(const int4*)(src + base + s * 1024);
            int dd[4] = {dr[s].x, dr[s].y, dr[s].z, dr[s].w};
            int ss[4] = {s4.x, s4.y, s4.z, s4.w};
            #pragma unroll
            for (int j = 0; j < 4; j++) {
                int d = dd[j];
                int b = d >> BSHIFT;
                int c = atomicAdd(&cur[b], 1);
                int slot = lpref[b] + c;
                ed[slot] = ((d & (BNODES - 1)) << 17) | ss[j];
                abuf[slot] = (unsigned short)b;
            }
        }
        __syncthreads();

        /* coalesced flush: consecutive lanes write consecutive run entries */
        for (int i = t; i < EPB; i += 256) {
            int b = abuf[i];
            int off = hist[b] + (i - lpref[b]);
            if (off < BCAP) ebuf[b * BCAP + off] = ed[i];
        }
    } else {
        /* ----- GEMM role (proven r9) ----- */
        __bf16* wh = (__bf16*)smraw;
        __bf16* wl = wh + 8192;
        for (int e = t; e < 8192; e += 256) {
            int c = e >> 9, l = (e >> 3) & 63, j = e & 7;
            int k = c * 32 + ((l >> 4) << 3) + j;
            int n = l & 15;
            float wv = W1[k * HID + n];
            __bf16 h = (__bf16)wv;
            wh[e] = h;
            wl[e] = (__bf16)(wv - (float)h);
        }
        __syncthreads();

        int wave = t >> 6, lane = t & 63;
        int q = lane >> 4, m = lane & 15;
        int row0 = (blockIdx.x - NPART) * 64 + wave * 16;
        int rowa = row0 + m;
        if (rowa >= N_NODES) rowa = N_NODES - 1;
        const float* xr = x + (size_t)rowa * F_IN + q * 8;

        floatx4 acc = {0.f, 0.f, 0.f, 0.f};
        #pragma unroll 4
        for (int c = 0; c < 16; c++) {
            float4 a0 = *(const float4*)(xr + c * 32);
            float4 a1 = *(const float4*)(xr + c * 32 + 4);
            float xv[8] = {a0.x, a0.y, a0.z, a0.w, a1.x, a1.y, a1.z, a1.w};
            bf16x8 ah, al;
            #pragma unroll
            for (int j = 0; j < 8; j++) {
                __bf16 h = (__bf16)xv[j];
                ah[j] = h;
                al[j] = (__bf16)(xv[j] - (float)h);
            }
            bf16x8 bh = *(const bf16x8*)&wh[(c * 64 + lane) * 8];
            bf16x8 bl = *(const bf16x8*)&wl[(c * 64 + lane) * 8];
            acc = __builtin_amdgcn_mfma_f32_16x16x32_bf16(ah, bh, acc, 0, 0, 0);
            acc = __builtin_amdgcn_mfma_f32_16x16x32_bf16(ah, bl, acc, 0, 0, 0);
            acc = __builtin_amdgcn_mfma_f32_16x16x32_bf16(al, bh, acc, 0, 0, 0);
        }
        #pragma unroll
        for (int r = 0; r < 4; r++) {
            int grow = row0 + q * 4 + r;
            if (grow < N_NODES)
                h1u[grow * HID + (lane & 15)] = (_Float16)acc[r];
        }
    }
}

/* ---------------- per-bucket counting sort -> dense CSR (proven r9)
 * + epilogue: scale this bucket's h1u rows by dinv (deg is in cnt[]) ---------------- */
__global__ __launch_bounds__(256) void k_sortb(const int* __restrict__ gcnt,
                                               const int* __restrict__ ebuf,
                                               int* __restrict__ col,
                                               int* __restrict__ rinfo,
                                               _Float16* __restrict__ h1) {
    __shared__ int ed[BCAP];
    __shared__ int cnt[BNODES];
    __shared__ int pref[BNODES];
    int b = blockIdx.x, t = threadIdx.x;

    int partial = 0;
    for (int i = t; i < b; i += 256) partial += gcnt[i];
    pref[t] = partial;
    __syncthreads();
    for (int off = 128; off; off >>= 1) {
        if (t < off) pref[t] += pref[t + off];
        __syncthreads();
    }
    int gbase = pref[0];
    __syncthreads();

    int ne = gcnt[b];
    if (ne > BCAP) ne = BCAP;
    cnt[t] = 0;
    __syncthreads();
    for (int i = t; i < ne; i += 256) {
        int e = ebuf[b * BCAP + i];
        ed[i] = e;
        atomicAdd(&cnt[e >> 17], 1);
    }
    __syncthreads();
    int c = cnt[t];
    pref[t] = c;
    __syncthreads();
    for (int off = 1; off < 256; off <<= 1) {
        int add = (t >= off) ? pref[t - off] : 0;
        __syncthreads();
        pref[t] += add;
        __syncthreads();
    }
    int start = pref[t] - c;
    int v = b * BNODES + t;
    if (v < N_NODES) {
        rinfo[v] = (c << 22) | (gbase + start);
        float dv = rsqrtf((float)(c + 1));
        f16x4* row = (f16x4*)(h1 + (size_t)v * HID);
        #pragma unroll
        for (int r = 0; r < 4; r++) {
            f16x4 vv = row[r];
            vv[0] = (_Float16)(dv * (float)vv[0]);
            vv[1] = (_Float16)(dv * (float)vv[1]);
            vv[2] = (_Float16)(dv * (float)vv[2]);
            vv[3] = (_Float16)(dv * (float)vv[3]);
            row[r] = vv;
        }
    }
    cnt[t] = start;
    __syncthreads();
    for (int i = t; i < ne; i += 256) {
        int e = ed[i];
        int pos = atomicAdd(&cnt[e >> 17], 1);
        col[gbase + pos] = e & 0x1FFFF;
    }
}

#define ACC4(gv) { a0 += (float)gv[0]; a1 += (float)gv[1]; \
                   a2 += (float)gv[2]; a3 += (float)gv[3]; }

/* ---------------- layer-1 aggregate: 4 lanes/node, f16x4 gathers (proven r8/r9) ---------------- */
__global__ __launch_bounds__(256) void k_agg1(const _Float16* __restrict__ h1s,
        const int* __restrict__ rinfo, const int* __restrict__ col,
        const float* __restrict__ b1, _Float16* __restrict__ ys) {
    int g = blockIdx.x * 256 + threadIdx.x;
    int v = g >> 2, q = g & 3;
    if (v >= N_NODES) return;
    int ri = rinfo[v];
    int beg = ri & 0x3FFFFF;
    int deg = (ri >> 22) & 0x3FF;
    int end = beg + deg;
    const f16x4* tab = (const f16x4*)h1s;
    float a0 = 0.f, a1 = 0.f, a2 = 0.f, a3 = 0.f;
    int j = beg;
    for (; j + 7 < end; j += 8) {
        int c0 = col[j],     c1 = col[j + 1], c2 = col[j + 2], c3 = col[j + 3];
        int c4 = col[j + 4], c5 = col[j + 5], c6 = col[j + 6], c7 = col[j + 7];
        f16x4 g0 = tab[c0 * 4 + q], g1 = tab[c1 * 4 + q];
        f16x4 g2 = tab[c2 * 4 + q], g3 = tab[c3 * 4 + q];
        f16x4 g4 = tab[c4 * 4 + q], g5 = tab[c5 * 4 + q];
        f16x4 g6 = tab[c6 * 4 + q], g7 = tab[c7 * 4 + q];
        ACC4(g0) ACC4(g1) ACC4(g2) ACC4(g3)
        ACC4(g4) ACC4(g5) ACC4(g6) ACC4(g7)
    }
    for (; j < end; j++) {
        f16x4 gv = tab[col[j] * 4 + q];
        ACC4(gv)
    }
    f16x4 sv = tab[v * 4 + q];          /* self loop (h1s dinv-scaled in k_sortb) */
    ACC4(sv)
    float dv = rsqrtf((float)(deg + 1));
    f16x4 o;
    o[0] = (_Float16)(dv * fmaxf(dv * a0 + b1[q * 4 + 0], 0.f));
    o[1] = (_Float16)(dv * fmaxf(dv * a1 + b1[q * 4 + 1], 0.f));
    o[2] = (_Float16)(dv * fmaxf(dv * a2 + b1[q * 4 + 2], 0.f));
    o[3] = (_Float16)(dv * fmaxf(dv * a3 + b1[q * 4 + 3], 0.f));
    ((f16x4*)ys)[v * 4 + q] = o;        /* pre-scaled for layer 2 */
}

/* ---------------- layer-2 aggregate + W2 + bias + log_softmax (proven r8/r9) ---------------- */
__global__ __launch_bounds__(256) void k_agg2(const _Float16* __restrict__ ys,
        const int* __restrict__ rinfo, const int* __restrict__ col,
        const float* __restrict__ W2, const float* __restrict__ b2,
        float* __restrict__ out) {
    __shared__ float w2s[HID * NCLS];
    __shared__ float b2s[NCLS];
    int t = threadIdx.x;
    for (int i = t; i < HID * NCLS; i += 256) w2s[i] = W2[i];
    if (t < NCLS) b2s[t] = b2[t];
    __syncthreads();

    int g = blockIdx.x * 256 + t;
    int v = g >> 2, q = g & 3;
    if (v >= N_NODES) return;
    int ri = rinfo[v];
    int beg = ri & 0x3FFFFF;
    int deg = (ri >> 22) & 0x3FF;
    int end = beg + deg;
    const f16x4* tab = (const f16x4*)ys;
    float a0 = 0.f, a1 = 0.f, a2 = 0.f, a3 = 0.f;
    int j = beg;
    for (; j + 7 < end; j += 8) {
        int c0 = col[j],     c1 = col[j + 1], c2 = col[j + 2], c3 = col[j + 3];
        int c4 = col[j + 4], c5 = col[j + 5], c6 = col[j + 6], c7 = col[j + 7];
        f16x4 g0 = tab[c0 * 4 + q], g1 = tab[c1 * 4 + q];
        f16x4 g2 = tab[c2 * 4 + q], g3 = tab[c3 * 4 + q];
        f16x4 g4 = tab[c4 * 4 + q], g5 = tab[c5 * 4 + q];
        f16x4 g6 = tab[c6 * 4 + q], g7 = tab[c7 * 4 + q];
        ACC4(g0) ACC4(g1) ACC4(g2) ACC4(g3)
        ACC4(g4) ACC4(g5) ACC4(g6) ACC4(g7)
    }
    for (; j < end; j++) {
        f16x4 gv = tab[col[j] * 4 + q];
        ACC4(gv)
    }
    f16x4 sv = tab[v * 4 + q];          /* self loop */
    ACC4(sv)
    float dv = rsqrtf((float)(deg + 1));
    float tv[4] = {dv * a0, dv * a1, dv * a2, dv * a3};

    float lg[10];
    #pragma unroll
    for (int i = 0; i < 10; i++) lg[i] = b2s[q * 10 + i];
    #pragma unroll
    for (int k = 0; k < 16; k++) {
        float tk = __shfl(tv[k & 3], k >> 2, 4);
        #pragma unroll
        for (int i = 0; i < 10; i++)
            lg[i] = fmaf(tk, w2s[k * NCLS + q * 10 + i], lg[i]);
    }
    float mx = lg[0];
    #pragma unroll
    for (int i = 1; i < 10; i++) mx = fmaxf(mx, lg[i]);
    mx = fmaxf(mx, __shfl_xor(mx, 1, 4));
    mx = fmaxf(mx, __shfl_xor(mx, 2, 4));
    float s = 0.f;
    #pragma unroll
    for (int i = 0; i < 10; i++) s += __expf(lg[i] - mx);
    s += __shfl_xor(s, 1, 4);
    s += __shfl_xor(s, 2, 4);
    float lse = mx + __logf(s);
    #pragma unroll
    for (int i = 0; i < 10; i++) out[v * NCLS + q * 10 + i] = lg[i] - lse;
}

extern "C" void kernel_launch(void* const* d_in, const int* in_sizes, int n_in,
                              void* d_out, int out_size, void* d_ws, size_t ws_size,
                              hipStream_t stream) {
    const float* x  = (const float*)d_in[0];
    const int*   ei = (const int*)d_in[1];
    const float* W1 = (const float*)d_in[2];
    const float* b1 = (const float*)d_in[3];
    const float* W2 = (const float*)d_in[4];
    const float* b2 = (const float*)d_in[5];
    float* out = (float*)d_out;
    const int* src = ei;
    const int* dst = ei + NEDGE;

    char* w = (char*)d_ws;
    size_t o = 0;
    auto alloc = [&](size_t bytes) -> char* {
        char* p = w + o;
        o += (bytes + 511) & ~(size_t)511;
        return p;
    };
    int*      gcnt  = (int*)alloc((size_t)NBUCK * 4);
    int*      rinfo = (int*)alloc((size_t)N_NODES * 4);
    int*      col   = (int*)alloc((size_t)NEDGE * 4);       /* 12.8 MB dense CSR */
    int*      ebuf  = (int*)alloc((size_t)NBUCK * BCAP * 4);/* 13.8 MB */
    _Float16* h1s   = (_Float16*)alloc((size_t)N_NODES * HID * 2);
    _Float16* ys    = (_Float16*)alloc((size_t)N_NODES * HID * 2);
    /* total ~33.5 MB */

    hipMemsetAsync(gcnt, 0, (size_t)NBUCK * 4, stream);

    k_partgemm<<<NPART + NGEMM, 256, 0, stream>>>(src, dst, gcnt, ebuf, x, W1, h1s);
    k_sortb   <<<NBUCK, 256, 0, stream>>>(gcnt, ebuf, col, rinfo, h1s);
    k_agg1    <<<(N_NODES * 4 + 255) / 256, 256, 0, stream>>>(h1s, rinfo, col, b1, ys);
    k_agg2    <<<(N_NODES * 4 + 255) / 256, 256, 0, stream>>>(ys, rinfo, col, W2, b2, out);
}

// Round 12
// 417.234 us; speedup vs baseline: 2.5375x; 1.0162x over previous
//
#include <hip/hip_runtime.h>

#define N_NODES 100000
#define NEDGE   3200000
#define F_IN    512
#define HID     16
#define NCLS    40

/* ---- dst-bucket partition geometry ---- */
#define BSHIFT  8
#define BNODES  256                                  /* nodes per bucket */
#define NBUCK   ((N_NODES + BNODES - 1) / BNODES)    /* 391 */
#define BCAP    8832    /* mean 8192, sd ~90 -> +7 sigma */
#define EPB     5120    /* edges per partition block: 256 thr x 4 x 5 */
#define NPART   (NEDGE / EPB)                        /* 625, exact */
#define NGEMM   ((N_NODES + 63) / 64)                /* 1563 */

typedef __bf16 bf16x8 __attribute__((ext_vector_type(8)));
typedef float floatx4 __attribute__((ext_vector_type(4)));
typedef float fltx4 __attribute__((ext_vector_type(4)));   /* for nontemporal loads */
typedef _Float16 f16x4 __attribute__((ext_vector_type(4)));

/* ---------------- fused: edge partition + GEMM1 (proven r10, + nt x loads) ---------------- */
__global__ __launch_bounds__(256) void k_partgemm(
        const int* __restrict__ src, const int* __restrict__ dst,
        int* __restrict__ gcnt, int* __restrict__ ebuf,
        const float* __restrict__ x, const float* __restrict__ W1,
        _Float16* __restrict__ h1u) {
    __shared__ char smraw[36864];
    int t = threadIdx.x;

    if (blockIdx.x < NPART) {
        /* ----- partition role with LDS sort (proven r10) ----- */
        int* hist  = (int*)smraw;
        int* lpref = hist + 512;
        int* cur   = lpref + 512;
        int* ed    = cur + 512;
        unsigned short* abuf = (unsigned short*)(ed + EPB);

        for (int i = t; i < NBUCK; i += 256) hist[i] = 0;
        __syncthreads();

        int base = blockIdx.x * EPB + t * 4;
        int4 dr[5];
        #pragma unroll
        for (int s = 0; s < 5; s++) {
            dr[s] = *(const int4*)(dst + base + s * 1024);
            atomicAdd(&hist[dr[s].x >> BSHIFT], 1);
            atomicAdd(&hist[dr[s].y >> BSHIFT], 1);
            atomicAdd(&hist[dr[s].z >> BSHIFT], 1);
            atomicAdd(&hist[dr[s].w >> BSHIFT], 1);
        }
        __syncthreads();

        int c0 = 0, c1 = 0;
        if (t < 196) {
            c0 = hist[2 * t];
            c1 = (2 * t + 1 < NBUCK) ? hist[2 * t + 1] : 0;
        }
        int sums = c0 + c1;
        cur[t] = sums;
        __syncthreads();
        for (int off = 1; off < 256; off <<= 1) {
            int add = (t >= off) ? cur[t - off] : 0;
            __syncthreads();
            cur[t] += add;
            __syncthreads();
        }
        if (t < 196) {
            int excl = cur[t] - sums;
            lpref[2 * t] = excl;
            if (2 * t + 1 < NBUCK) lpref[2 * t + 1] = excl + c0;
        }
        __syncthreads();

        for (int i = t; i < NBUCK; i += 256) {
            int c = hist[i];
            hist[i] = c ? atomicAdd(&gcnt[i], c) : 0;
        }
        for (int i = t; i < 512; i += 256) cur[i] = 0;
        __syncthreads();

        #pragma unroll
        for (int s = 0; s < 5; s++) {
            int4 s4 = *(const int4*)(src + base + s * 1024);
            int dd[4] = {dr[s].x, dr[s].y, dr[s].z, dr[s].w};
            int ss[4] = {s4.x, s4.y, s4.z, s4.w};
            #pragma unroll
            for (int j = 0; j < 4; j++) {
                int d = dd[j];
                int b = d >> BSHIFT;
                int c = atomicAdd(&cur[b], 1);
                int slot = lpref[b] + c;
                ed[slot] = ((d & (BNODES - 1)) << 17) | ss[j];
                abuf[slot] = (unsigned short)b;
            }
        }
        __syncthreads();

        for (int i = t; i < EPB; i += 256) {
            int b = abuf[i];
            int off = hist[b] + (i - lpref[b]);
            if (off < BCAP) ebuf[b * BCAP + off] = ed[i];
        }
    } else {
        /* ----- GEMM role (proven r9/r10; x loads nontemporal via ext-vector) ----- */
        __bf16* wh = (__bf16*)smraw;
        __bf16* wl = wh + 8192;
        for (int e = t; e < 8192; e += 256) {
            int c = e >> 9, l = (e >> 3) & 63, j = e & 7;
            int k = c * 32 + ((l >> 4) << 3) + j;
            int n = l & 15;
            float wv = W1[k * HID + n];
            __bf16 h = (__bf16)wv;
            wh[e] = h;
            wl[e] = (__bf16)(wv - (float)h);
        }
        __syncthreads();

        int wave = t >> 6, lane = t & 63;
        int q = lane >> 4, m = lane & 15;
        int row0 = (blockIdx.x - NPART) * 64 + wave * 16;
        int rowa = row0 + m;
        if (rowa >= N_NODES) rowa = N_NODES - 1;
        const float* xr = x + (size_t)rowa * F_IN + q * 8;

        floatx4 acc = {0.f, 0.f, 0.f, 0.f};
        #pragma unroll 4
        for (int c = 0; c < 16; c++) {
            fltx4 a0 = __builtin_nontemporal_load((const fltx4*)(xr + c * 32));
            fltx4 a1 = __builtin_nontemporal_load((const fltx4*)(xr + c * 32 + 4));
            float xv[8] = {a0[0], a0[1], a0[2], a0[3], a1[0], a1[1], a1[2], a1[3]};
            bf16x8 ah, al;
            #pragma unroll
            for (int j = 0; j < 8; j++) {
                __bf16 h = (__bf16)xv[j];
                ah[j] = h;
                al[j] = (__bf16)(xv[j] - (float)h);
            }
            bf16x8 bh = *(const bf16x8*)&wh[(c * 64 + lane) * 8];
            bf16x8 bl = *(const bf16x8*)&wl[(c * 64 + lane) * 8];
            acc = __builtin_amdgcn_mfma_f32_16x16x32_bf16(ah, bh, acc, 0, 0, 0);
            acc = __builtin_amdgcn_mfma_f32_16x16x32_bf16(ah, bl, acc, 0, 0, 0);
            acc = __builtin_amdgcn_mfma_f32_16x16x32_bf16(al, bh, acc, 0, 0, 0);
        }
        #pragma unroll
        for (int r = 0; r < 4; r++) {
            int grow = row0 + q * 4 + r;
            if (grow < N_NODES)
                h1u[grow * HID + (lane & 15)] = (_Float16)acc[r];
        }
    }
}

/* ---------------- per-bucket counting sort -> dense CSR + h1 dinv scale (proven r9/r10) ---------------- */
__global__ __launch_bounds__(256) void k_sortb(const int* __restrict__ gcnt,
                                               const int* __restrict__ ebuf,
                                               int* __restrict__ col,
                                               int* __restrict__ rinfo,
                                               _Float16* __restrict__ h1) {
    __shared__ int ed[BCAP];
    __shared__ int cnt[BNODES];
    __shared__ int pref[BNODES];
    int b = blockIdx.x, t = threadIdx.x;

    int partial = 0;
    for (int i = t; i < b; i += 256) partial += gcnt[i];
    pref[t] = partial;
    __syncthreads();
    for (int off = 128; off; off >>= 1) {
        if (t < off) pref[t] += pref[t + off];
        __syncthreads();
    }
    int gbase = pref[0];
    __syncthreads();

    int ne = gcnt[b];
    if (ne > BCAP) ne = BCAP;
    cnt[t] = 0;
    __syncthreads();
    for (int i = t; i < ne; i += 256) {
        int e = ebuf[b * BCAP + i];
        ed[i] = e;
        atomicAdd(&cnt[e >> 17], 1);
    }
    __syncthreads();
    int c = cnt[t];
    pref[t] = c;
    __syncthreads();
    for (int off = 1; off < 256; off <<= 1) {
        int add = (t >= off) ? pref[t - off] : 0;
        __syncthreads();
        pref[t] += add;
        __syncthreads();
    }
    int start = pref[t] - c;
    int v = b * BNODES + t;
    if (v < N_NODES) {
        rinfo[v] = (c << 22) | (gbase + start);
        float dv = rsqrtf((float)(c + 1));
        f16x4* row = (f16x4*)(h1 + (size_t)v * HID);
        #pragma unroll
        for (int r = 0; r < 4; r++) {
            f16x4 vv = row[r];
            vv[0] = (_Float16)(dv * (float)vv[0]);
            vv[1] = (_Float16)(dv * (float)vv[1]);
            vv[2] = (_Float16)(dv * (float)vv[2]);
            vv[3] = (_Float16)(dv * (float)vv[3]);
            row[r] = vv;
        }
    }
    cnt[t] = start;
    __syncthreads();
    for (int i = t; i < ne; i += 256) {
        int e = ed[i];
        int pos = atomicAdd(&cnt[e >> 17], 1);
        col[gbase + pos] = e & 0x1FFFF;
    }
}

#define ACC4(gv) { a0 += (float)gv[0]; a1 += (float)gv[1]; \
                   a2 += (float)gv[2]; a3 += (float)gv[3]; }
#define G1(ci)   { f16x4 gv = tab[(ci) * 4 + q]; ACC4(gv) }
#define G4(c4)   { f16x4 gA = tab[c4.x * 4 + q], gB = tab[c4.y * 4 + q]; \
                   f16x4 gC = tab[c4.z * 4 + q], gD = tab[c4.w * 4 + q]; \
                   ACC4(gA) ACC4(gB) ACC4(gC) ACC4(gD) }

/* ---------------- layer-1 aggregate: 4 lanes/node, int4 col batches of 16 ----------------
 * col loaded as aligned int4 (broadcast across the 4 lanes): 4 independent
 * index loads + 16 independent gathers per iteration -> ~2x MLP vs the r8
 * scalar-col batch-8 chain. <=3-iter scalar head aligns col to 16B. */
__global__ __launch_bounds__(256) void k_agg1(const _Float16* __restrict__ h1s,
        const int* __restrict__ rinfo, const int* __restrict__ col,
        const float* __restrict__ b1, _Float16* __restrict__ ys) {
    int g = blockIdx.x * 256 + threadIdx.x;
    int v = g >> 2, q = g & 3;
    if (v >= N_NODES) return;
    int ri = rinfo[v];
    int beg = ri & 0x3FFFFF;
    int deg = (ri >> 22) & 0x3FF;
    int end = beg + deg;
    const f16x4* tab = (const f16x4*)h1s;
    float a0 = 0.f, a1 = 0.f, a2 = 0.f, a3 = 0.f;

    int j = beg;
    int hend = (beg + ((4 - (beg & 3)) & 3));
    if (hend > end) hend = end;
    for (; j < hend; j++) G1(col[j])
    for (; j + 15 < end; j += 16) {
        int4 ca = *(const int4*)(col + j);
        int4 cb = *(const int4*)(col + j + 4);
        int4 cc = *(const int4*)(col + j + 8);
        int4 cd = *(const int4*)(col + j + 12);
        G4(ca) G4(cb) G4(cc) G4(cd)
    }
    for (; j + 3 < end; j += 4) {
        int4 ca = *(const int4*)(col + j);
        G4(ca)
    }
    for (; j < end; j++) G1(col[j])

    f16x4 sv = tab[v * 4 + q];          /* self loop (h1s dinv-scaled in k_sortb) */
    ACC4(sv)
    float dv = rsqrtf((float)(deg + 1));
    f16x4 o;
    o[0] = (_Float16)(dv * fmaxf(dv * a0 + b1[q * 4 + 0], 0.f));
    o[1] = (_Float16)(dv * fmaxf(dv * a1 + b1[q * 4 + 1], 0.f));
    o[2] = (_Float16)(dv * fmaxf(dv * a2 + b1[q * 4 + 2], 0.f));
    o[3] = (_Float16)(dv * fmaxf(dv * a3 + b1[q * 4 + 3], 0.f));
    ((f16x4*)ys)[v * 4 + q] = o;        /* pre-scaled for layer 2 */
}

/* ---------------- layer-2 aggregate + W2 + bias + log_softmax ---------------- */
__global__ __launch_bounds__(256) void k_agg2(const _Float16* __restrict__ ys,
        const int* __restrict__ rinfo, const int* __restrict__ col,
        const float* __restrict__ W2, const float* __restrict__ b2,
        float* __restrict__ out) {
    __shared__ float w2s[HID * NCLS];
    __shared__ float b2s[NCLS];
    int t = threadIdx.x;
    for (int i = t; i < HID * NCLS; i += 256) w2s[i] = W2[i];
    if (t < NCLS) b2s[t] = b2[t];
    __syncthreads();

    int g = blockIdx.x * 256 + t;
    int v = g >> 2, q = g & 3;
    if (v >= N_NODES) return;
    int ri = rinfo[v];
    int beg = ri & 0x3FFFFF;
    int deg = (ri >> 22) & 0x3FF;
    int end = beg + deg;
    const f16x4* tab = (const f16x4*)ys;
    float a0 = 0.f, a1 = 0.f, a2 = 0.f, a3 = 0.f;

    int j = beg;
    int hend = (beg + ((4 - (beg & 3)) & 3));
    if (hend > end) hend = end;
    for (; j < hend; j++) G1(col[j])
    for (; j + 15 < end; j += 16) {
        int4 ca = *(const int4*)(col + j);
        int4 cb = *(const int4*)(col + j + 4);
        int4 cc = *(const int4*)(col + j + 8);
        int4 cd = *(const int4*)(col + j + 12);
        G4(ca) G4(cb) G4(cc) G4(cd)
    }
    for (; j + 3 < end; j += 4) {
        int4 ca = *(const int4*)(col + j);
        G4(ca)
    }
    for (; j < end; j++) G1(col[j])

    f16x4 sv = tab[v * 4 + q];          /* self loop */
    ACC4(sv)
    float dv = rsqrtf((float)(deg + 1));
    float tv[4] = {dv * a0, dv * a1, dv * a2, dv * a3};

    float lg[10];
    #pragma unroll
    for (int i = 0; i < 10; i++) lg[i] = b2s[q * 10 + i];
    #pragma unroll
    for (int k = 0; k < 16; k++) {
        float tk = __shfl(tv[k & 3], k >> 2, 4);
        #pragma unroll
        for (int i = 0; i < 10; i++)
            lg[i] = fmaf(tk, w2s[k * NCLS + q * 10 + i], lg[i]);
    }
    float mx = lg[0];
    #pragma unroll
    for (int i = 1; i < 10; i++) mx = fmaxf(mx, lg[i]);
    mx = fmaxf(mx, __shfl_xor(mx, 1, 4));
    mx = fmaxf(mx, __shfl_xor(mx, 2, 4));
    float s = 0.f;
    #pragma unroll
    for (int i = 0; i < 10; i++) s += __expf(lg[i] - mx);
    s += __shfl_xor(s, 1, 4);
    s += __shfl_xor(s, 2, 4);
    float lse = mx + __logf(s);
    #pragma unroll
    for (int i = 0; i < 10; i++) out[v * NCLS + q * 10 + i] = lg[i] - lse;
}

extern "C" void kernel_launch(void* const* d_in, const int* in_sizes, int n_in,
                              void* d_out, int out_size, void* d_ws, size_t ws_size,
                              hipStream_t stream) {
    const float* x  = (const float*)d_in[0];
    const int*   ei = (const int*)d_in[1];
    const float* W1 = (const float*)d_in[2];
    const float* b1 = (const float*)d_in[3];
    const float* W2 = (const float*)d_in[4];
    const float* b2 = (const float*)d_in[5];
    float* out = (float*)d_out;
    const int* src = ei;
    const int* dst = ei + NEDGE;

    char* w = (char*)d_ws;
    size_t o = 0;
    auto alloc = [&](size_t bytes) -> char* {
        char* p = w + o;
        o += (bytes + 511) & ~(size_t)511;
        return p;
    };
    int*      gcnt  = (int*)alloc((size_t)NBUCK * 4);
    int*      rinfo = (int*)alloc((size_t)N_NODES * 4);
    int*      col   = (int*)alloc((size_t)NEDGE * 4);       /* 12.8 MB dense CSR */
    int*      ebuf  = (int*)alloc((size_t)NBUCK * BCAP * 4);/* 13.8 MB */
    _Float16* h1s   = (_Float16*)alloc((size_t)N_NODES * HID * 2);
    _Float16* ys    = (_Float16*)alloc((size_t)N_NODES * HID * 2);
    /* total ~33.5 MB */

    (void)hipMemsetAsync(gcnt, 0, (size_t)NBUCK * 4, stream);

    k_partgemm<<<NPART + NGEMM, 256, 0, stream>>>(src, dst, gcnt, ebuf, x, W1, h1s);
    k_sortb   <<<NBUCK, 256, 0, stream>>>(gcnt, ebuf, col, rinfo, h1s);
    k_agg1    <<<(N_NODES * 4 + 255) / 256, 256, 0, stream>>>(h1s, rinfo, col, b1, ys);
    k_agg2    <<<(N_NODES * 4 + 255) / 256, 256, 0, stream>>>(ys, rinfo, col, W2, b2, out);
}